// Round 6
// baseline (239.531 us; speedup 1.0000x reference)
//
#include <hip/hip_runtime.h>
#include <stdint.h>
#include <stddef.h>

#define B_      8
#define T_      16
#define NX_     256
#define NZ_     64
#define D_      1024
#define HEADS_  8
#define DHEAD_  64
#define INNER_  512
#define NKEY_   320          // NX_ + NZ_
#define NBT_    128          // B_*T_

typedef __attribute__((ext_vector_type(8))) short     short8;
typedef __attribute__((ext_vector_type(4))) float     f32x4;
typedef __attribute__((ext_vector_type(8))) unsigned short u16x8;

__device__ __forceinline__ unsigned short f2bf(float f) {
    union { float f; unsigned int u; } v; v.f = f;
    unsigned int u = v.u;
    return (unsigned short)((u + 0x7fffu + ((u >> 16) & 1u)) >> 16);
}

__device__ __forceinline__ void async16(unsigned short* lds, const unsigned short* g) {
    __builtin_amdgcn_global_load_lds(
        (const __attribute__((address_space(1))) void*)g,
        (__attribute__((address_space(3))) void*)lds, 16, 0, 0);
}

// ---------------------------------------------------------------------------
// mask normalization: handles both bool-byte and int32 storage of mask[128]
// ---------------------------------------------------------------------------
__global__ void mask_kernel(const unsigned char* __restrict__ mraw,
                            int* __restrict__ maskN) {
    int lane = threadIdx.x;                 // 64 threads
    unsigned char b0 = mraw[lane];
    unsigned char b1 = mraw[lane + 64];
    bool nz = (((lane) & 3) != 0 && b0 != 0) || (((lane + 64) & 3) != 0 && b1 != 0);
    unsigned long long ball = __ballot(nz ? 1 : 0);
    bool isBool = (ball != 0ull);
    int v0, v1;
    if (isBool) { v0 = b0; v1 = b1; }
    else        { v0 = mraw[4 * lane]; v1 = mraw[4 * (lane + 64)]; }
    maskN[lane]      = v0 ? 1 : 0;
    maskN[lane + 64] = v1 ? 1 : 0;
}

// ---------------------------------------------------------------------------
// weight prep: f32 -> bf16, transposed to [N][K]
// ---------------------------------------------------------------------------
__global__ __launch_bounds__(256) void wprep_kernel(
        const float* __restrict__ Wq, const float* __restrict__ Wkv,
        const float* __restrict__ Wo,
        unsigned short* __restrict__ WqT, unsigned short* __restrict__ WkvT,
        unsigned short* __restrict__ WoT) {
    size_t id = (size_t)blockIdx.x * 256 + threadIdx.x;
    if (id < 524288) {                       // WqT[512][1024] <- Wq[1024][512]
        int n = (int)(id >> 10), k = (int)(id & 1023);
        WqT[id] = f2bf(Wq[(size_t)k * 512 + n]);
    } else if (id < 524288 + 1048576) {      // WkvT[1024][1024] <- Wkv[1024][1024]
        size_t j = id - 524288;
        int n = (int)(j >> 10), k = (int)(j & 1023);
        WkvT[j] = f2bf(Wkv[(size_t)k * 1024 + n]);
    } else {                                 // WoT[1024][512] <- Wo[512][1024]
        size_t j = id - 1572864;
        int n = (int)(j >> 9), k = (int)(j & 511);
        WoT[j] = f2bf(Wo[(size_t)k * 1024 + n]);
    }
}

// ---------------------------------------------------------------------------
// LayerNorm rows of x (32768) and latents (8192) -> bf16 packed kvin
// kvin[bt][0..255][1024] = xn rows, kvin[bt][256..319][1024] = zn rows
// ---------------------------------------------------------------------------
__global__ __launch_bounds__(256) void ln_kernel(
        const float* __restrict__ x, const float* __restrict__ lat,
        const float* __restrict__ gm, const float* __restrict__ bm,
        const float* __restrict__ gl, const float* __restrict__ bl,
        const int* __restrict__ maskN,
        unsigned short* __restrict__ kvin) {
    int row = blockIdx.x;
    const float* src; unsigned short* dst; const float* g; const float* b;
    int bt;
    if (row < NBT_ * NX_) {
        bt = row >> 8;
        src = x + (size_t)row * D_;
        dst = kvin + ((size_t)bt * NKEY_ + (row & 255)) * D_;
        g = gm; b = bm;
    } else {
        int r = row - NBT_ * NX_;
        bt = r >> 6;
        src = lat + (size_t)r * D_;
        dst = kvin + ((size_t)bt * NKEY_ + 256 + (r & 63)) * D_;
        g = gl; b = bl;
    }
    if (!maskN[bt]) return;                  // masked (b,t): values never read
    int t = threadIdx.x;
    float4 v = reinterpret_cast<const float4*>(src)[t];
    float s  = v.x + v.y + v.z + v.w;
    float sq = v.x * v.x + v.y * v.y + v.z * v.z + v.w * v.w;
    #pragma unroll
    for (int off = 32; off > 0; off >>= 1) {
        s  += __shfl_down(s, off);
        sq += __shfl_down(sq, off);
    }
    __shared__ float red[8];
    int wid = t >> 6;
    if ((t & 63) == 0) { red[wid] = s; red[4 + wid] = sq; }
    __syncthreads();
    float stot = red[0] + red[1] + red[2] + red[3];
    float qtot = red[4] + red[5] + red[6] + red[7];
    float mean = stot * (1.0f / 1024.0f);
    float var  = qtot * (1.0f / 1024.0f) - mean * mean;
    float rstd = rsqrtf(var + 1e-5f);
    float4 gv = reinterpret_cast<const float4*>(g)[t];
    float4 bv = reinterpret_cast<const float4*>(b)[t];
    ushort4 o;
    o.x = f2bf((v.x - mean) * rstd * gv.x + bv.x);
    o.y = f2bf((v.y - mean) * rstd * gv.y + bv.y);
    o.z = f2bf((v.z - mean) * rstd * gv.z + bv.z);
    o.w = f2bf((v.w - mean) * rstd * gv.w + bv.w);
    *reinterpret_cast<ushort4*>(dst + 4 * t) = o;
}

// ---------------------------------------------------------------------------
// 4-phase spread-stage dbuf GEMM: 128x128 tile, BK=64, 4 waves.
// Per K-tile: 4 phases, each = {stage one 8KB half-tile (2 gload_lds) into
// buf^1, compute one C-quadrant (8 ds_read + 8 MFMA) from buf}; then ONE
// vmcnt(0) (loads are 1-4 phases old -> near-free) + ONE raw s_barrier.
// MODE 0: q  [8192][512]  = kvin-z rows @ WqT,  *0.125, bf16
// MODE 1: kv [40960][1024]= kvin @ WkvT -> k [bt][320][512], vT [bt][512][320]
// MODE 2: out[8192][1024] = ao @ WoT, f32, zeros for masked rows
// ---------------------------------------------------------------------------
template<int MODE>
__global__ __launch_bounds__(256) void gemm128_kernel(
        const unsigned short* __restrict__ A,
        const unsigned short* __restrict__ BT,
        const int* __restrict__ maskN,
        unsigned short* __restrict__ o_q,
        unsigned short* __restrict__ o_k,
        unsigned short* __restrict__ o_v,
        float* __restrict__ o_f) {
    constexpr int K     = (MODE == 2) ? 512 : 1024;
    constexpr int NSTEP = K / 64;                              // even (8 or 16)
    constexpr int NT    = (MODE == 0) ? 4 : 8;                 // N-tiles
    constexpr int CHUNK = (MODE == 1) ? 320 : (MODE == 0 ? 32 : 64);

    int swz = (blockIdx.x & 7) * CHUNK + (blockIdx.x >> 3);    // XCD-chunked
    int nt = swz % NT, mt = swz / NT;
    int m0 = mt * 128, n0 = nt * 128;
    int t = threadIdx.x;
    int lane = t & 63, wid = t >> 6;
    int lr = lane & 15, lg = lane >> 4;
    int wm = wid >> 1, wn = wid & 1;

    // mask skip: which bt's does this row-tile touch?
    int bt0, bt1;
    if (MODE == 1) { bt0 = m0 / NKEY_; bt1 = (m0 + 127) / NKEY_; }
    else           { bt0 = m0 >> 6;    bt1 = bt0 + 1; }
    bool any = false;
    for (int b = bt0; b <= bt1; b++) any |= (maskN[b] != 0);
    if (!any) {
        if (MODE == 2) {                       // masked out rows must be zero
            int r = t >> 1, cb = (t & 1) * 64;
            float4 z = make_float4(0.f, 0.f, 0.f, 0.f);
            float4* p = reinterpret_cast<float4*>(o_f + (size_t)(m0 + r) * 1024 + n0 + cb);
            #pragma unroll
            for (int j = 0; j < 16; j++) p[j] = z;
        }
        return;
    }

    __shared__ __align__(16) unsigned short As[2][8192];   // 2 x 128x64
    __shared__ __align__(16) unsigned short Bs[2][8192];

    // global staging pointers; index j = h*2 + r  (half h, round r)
    // row covered: m0/n0 + h*64 + r*32 + wid*8 + (lane>>3), col (lane&7)*8
    const unsigned short* Aptr[4];
    const unsigned short* Bptr[4];
    #pragma unroll
    for (int j = 0; j < 4; j++) {
        int h = j >> 1, r = j & 1;
        int row = m0 + h * 64 + r * 32 + wid * 8 + (lane >> 3);
        size_t srow;
        if (MODE == 0) { int bt = row >> 6; srow = (size_t)bt * NKEY_ + 256 + (row & 63); }
        else           srow = (size_t)row;
        Aptr[j] = A  + srow * K + (lane & 7) * 8;
        int brow = n0 + h * 64 + r * 32 + wid * 8 + (lane >> 3);
        Bptr[j] = BT + (size_t)brow * K + (lane & 7) * 8;
    }

    f32x4 acc[4][4];
    #pragma unroll
    for (int i = 0; i < 4; i++)
        #pragma unroll
        for (int j = 0; j < 4; j++) acc[i][j] = (f32x4){0.f, 0.f, 0.f, 0.f};

    // stage half H of matrix MAT (As/Aptr or Bs/Bptr) into buffer DSTBUF.
    // LDS dest is wave-uniform (wid*8 rows per wave, lane spreads 16B each).
    #define STAGE_HALF(DSTBUF, MAT, H)                                        \
        if (hasNext) {                                                        \
            async16(&MAT##s[DSTBUF][(H * 64 + wid * 8) * 64],      MAT##ptr[H * 2]);     \
            async16(&MAT##s[DSTBUF][(H * 64 + 32 + wid * 8) * 64], MAT##ptr[H * 2 + 1]); \
            MAT##ptr[H * 2] += 64; MAT##ptr[H * 2 + 1] += 64;                 \
        }

    #define QUAD(BUF, MH, NH)                                                 \
        {                                                                     \
            _Pragma("unroll")                                                 \
            for (int kc = 0; kc < 2; kc++) {                                  \
                short8 a0 = *reinterpret_cast<const short8*>(                 \
                    &As[BUF][(wm * 64 + MH * 32 + lr) * 64 + kc * 32 + lg * 8]);      \
                short8 a1 = *reinterpret_cast<const short8*>(                 \
                    &As[BUF][(wm * 64 + MH * 32 + 16 + lr) * 64 + kc * 32 + lg * 8]); \
                short8 b0 = *reinterpret_cast<const short8*>(                 \
                    &Bs[BUF][(wn * 64 + NH * 32 + lr) * 64 + kc * 32 + lg * 8]);      \
                short8 b1 = *reinterpret_cast<const short8*>(                 \
                    &Bs[BUF][(wn * 64 + NH * 32 + 16 + lr) * 64 + kc * 32 + lg * 8]); \
                acc[MH*2  ][NH*2  ] = __builtin_amdgcn_mfma_f32_16x16x32_bf16(a0, b0, acc[MH*2  ][NH*2  ], 0, 0, 0); \
                acc[MH*2  ][NH*2+1] = __builtin_amdgcn_mfma_f32_16x16x32_bf16(a0, b1, acc[MH*2  ][NH*2+1], 0, 0, 0); \
                acc[MH*2+1][NH*2  ] = __builtin_amdgcn_mfma_f32_16x16x32_bf16(a1, b0, acc[MH*2+1][NH*2  ], 0, 0, 0); \
                acc[MH*2+1][NH*2+1] = __builtin_amdgcn_mfma_f32_16x16x32_bf16(a1, b1, acc[MH*2+1][NH*2+1], 0, 0, 0); \
            }                                                                 \
        }

    // one K-tile: 4 interleaved {stage-half, quadrant} phases, then one
    // aged vmcnt(0) + one barrier.
    #define KTILE(BUF)                                                        \
        STAGE_HALF((BUF) ^ 1, A, 0) QUAD(BUF, 0, 0)                           \
        STAGE_HALF((BUF) ^ 1, A, 1) QUAD(BUF, 0, 1)                           \
        STAGE_HALF((BUF) ^ 1, B, 0) QUAD(BUF, 1, 0)                           \
        STAGE_HALF((BUF) ^ 1, B, 1) QUAD(BUF, 1, 1)                           \
        asm volatile("s_waitcnt vmcnt(0)" ::: "memory");                      \
        __builtin_amdgcn_s_barrier();

    // prologue: stage tile 0 into buf 0
    {
        const bool hasNext = true;
        STAGE_HALF(0, A, 0) STAGE_HALF(0, A, 1)
        STAGE_HALF(0, B, 0) STAGE_HALF(0, B, 1)
    }
    asm volatile("s_waitcnt vmcnt(0)" ::: "memory");
    __builtin_amdgcn_s_barrier();

    #pragma unroll 1
    for (int ks2 = 0; ks2 < NSTEP / 2; ks2++) {
        { const bool hasNext = true;                    KTILE(0) }  // tile 2k stages 2k+1
        { const bool hasNext = (ks2 + 1 < NSTEP / 2);   KTILE(1) }  // tile 2k+1 stages 2k+2
    }
    #undef KTILE
    #undef QUAD
    #undef STAGE_HALF

    #pragma unroll
    for (int mi = 0; mi < 4; mi++)
        #pragma unroll
        for (int ni = 0; ni < 4; ni++) {
            int gr0 = m0 + wm * 64 + mi * 16 + lg * 4;     // +r, never crosses bt
            int c   = n0 + wn * 64 + ni * 16 + lr;
            if (MODE == 0) {
                #pragma unroll
                for (int r = 0; r < 4; r++)
                    o_q[(size_t)(gr0 + r) * 512 + c] = f2bf(acc[mi][ni][r] * 0.125f);
            } else if (MODE == 1) {
                int bt = gr0 / NKEY_;
                int krow = gr0 - bt * NKEY_;
                if (c < 512) {
                    #pragma unroll
                    for (int r = 0; r < 4; r++)
                        o_k[((size_t)bt * NKEY_ + krow + r) * 512 + c] = f2bf(acc[mi][ni][r]);
                } else {
                    ushort4 pv;
                    pv.x = f2bf(acc[mi][ni][0]); pv.y = f2bf(acc[mi][ni][1]);
                    pv.z = f2bf(acc[mi][ni][2]); pv.w = f2bf(acc[mi][ni][3]);
                    *reinterpret_cast<ushort4*>(
                        o_v + ((size_t)bt * 512 + (c - 512)) * NKEY_ + krow) = pv;
                }
            } else {
                int bt = gr0 >> 6;
                bool live = maskN[bt] != 0;
                #pragma unroll
                for (int r = 0; r < 4; r++)
                    o_f[(size_t)(gr0 + r) * 1024 + c] = live ? acc[mi][ni][r] : 0.0f;
            }
        }
}

// ---------------------------------------------------------------------------
// fused attention per (b,t,h): sim = q @ k^T (64x320), softmax, out = attn @ v
// ---------------------------------------------------------------------------
__global__ __launch_bounds__(256) void attn_kernel(
        const unsigned short* __restrict__ q,
        const unsigned short* __restrict__ kbuf,
        const unsigned short* __restrict__ vbuf,   // vT [bt][512][320]
        const int* __restrict__ maskN,
        unsigned short* __restrict__ ao) {
    const int nwg = gridDim.x;                     // 1024
    int bid = (blockIdx.x & 7) * (nwg >> 3) + (blockIdx.x >> 3);
    int bt = bid >> 3, h = bid & 7;
    if (!maskN[bt]) return;
    int t = threadIdx.x, w = t >> 6, lane = t & 63;
    int lr = lane & 15, lg = lane >> 4;
    __shared__ __align__(16) unsigned short attn_s[4][16][328];

    const unsigned short* qrow = q + ((size_t)bt * 64 + w * 16 + lr) * 512 + h * 64;
    short8 qa0 = *reinterpret_cast<const short8*>(qrow + lg * 8);
    short8 qa1 = *reinterpret_cast<const short8*>(qrow + 32 + lg * 8);

    f32x4 acc[20];
    #pragma unroll
    for (int i = 0; i < 20; i++) acc[i] = (f32x4){0.f, 0.f, 0.f, 0.f};

    const unsigned short* kb = kbuf + (size_t)bt * NKEY_ * 512 + h * 64;
    #pragma unroll
    for (int nt2 = 0; nt2 < 20; nt2++) {
        const unsigned short* krow = kb + (size_t)(nt2 * 16 + lr) * 512;
        short8 b0 = *reinterpret_cast<const short8*>(krow + lg * 8);
        short8 b1 = *reinterpret_cast<const short8*>(krow + 32 + lg * 8);
        acc[nt2] = __builtin_amdgcn_mfma_f32_16x16x32_bf16(qa0, b0, acc[nt2], 0, 0, 0);
        acc[nt2] = __builtin_amdgcn_mfma_f32_16x16x32_bf16(qa1, b1, acc[nt2], 0, 0, 0);
    }

    float mx[4], sm[4];
    #pragma unroll
    for (int r = 0; r < 4; r++) mx[r] = -1e30f;
    #pragma unroll
    for (int nt2 = 0; nt2 < 20; nt2++)
        #pragma unroll
        for (int r = 0; r < 4; r++) mx[r] = fmaxf(mx[r], acc[nt2][r]);
    #pragma unroll
    for (int r = 0; r < 4; r++) {
        #pragma unroll
        for (int off = 1; off < 16; off <<= 1)
            mx[r] = fmaxf(mx[r], __shfl_xor(mx[r], off));
        sm[r] = 0.f;
    }
    #pragma unroll
    for (int nt2 = 0; nt2 < 20; nt2++)
        #pragma unroll
        for (int r = 0; r < 4; r++) {
            float p = __expf(acc[nt2][r] - mx[r]);
            acc[nt2][r] = p;
            sm[r] += p;
        }
    #pragma unroll
    for (int r = 0; r < 4; r++) {
        #pragma unroll
        for (int off = 1; off < 16; off <<= 1)
            sm[r] += __shfl_xor(sm[r], off);
        sm[r] = 1.0f / sm[r];
    }
    #pragma unroll
    for (int nt2 = 0; nt2 < 20; nt2++)
        #pragma unroll
        for (int r = 0; r < 4; r++)
            attn_s[w][lg * 4 + r][nt2 * 16 + lr] = f2bf(acc[nt2][r] * sm[r]);
    __syncthreads();

    f32x4 o[4];
    #pragma unroll
    for (int i = 0; i < 4; i++) o[i] = (f32x4){0.f, 0.f, 0.f, 0.f};
    const unsigned short* vb = vbuf + (size_t)bt * 512 * NKEY_ + (size_t)h * 64 * NKEY_;
    #pragma unroll
    for (int kc = 0; kc < 10; kc++) {
        short8 pa = *reinterpret_cast<const short8*>(&attn_s[w][lr][kc * 32 + lg * 8]);
        #pragma unroll
        for (int ni = 0; ni < 4; ni++) {
            short8 vf = *reinterpret_cast<const short8*>(
                vb + (size_t)(ni * 16 + lr) * NKEY_ + kc * 32 + lg * 8);
            o[ni] = __builtin_amdgcn_mfma_f32_16x16x32_bf16(pa, vf, o[ni], 0, 0, 0);
        }
    }
    #pragma unroll
    for (int ni = 0; ni < 4; ni++)
        #pragma unroll
        for (int r = 0; r < 4; r++)
            ao[((size_t)bt * 64 + w * 16 + lg * 4 + r) * 512 + h * 64 + ni * 16 + lr] =
                f2bf(o[ni][r]);
}

// ---------------------------------------------------------------------------
extern "C" void kernel_launch(void* const* d_in, const int* in_sizes, int n_in,
                              void* d_out, int out_size, void* d_ws, size_t ws_size,
                              hipStream_t stream) {
    const float* x            = (const float*)d_in[0];
    const float* lat          = (const float*)d_in[1];
    const unsigned char* mraw = (const unsigned char*)d_in[2];
    const float* gm           = (const float*)d_in[3];
    const float* bm           = (const float*)d_in[4];
    const float* gl           = (const float*)d_in[5];
    const float* bl           = (const float*)d_in[6];
    const float* Wq           = (const float*)d_in[7];
    const float* Wkv          = (const float*)d_in[8];
    const float* Wo           = (const float*)d_in[9];
    float* out = (float*)d_out;

    char* ws = (char*)d_ws;
    size_t off = 0;
    int* maskN = (int*)(ws + off);             off += 1024;
    unsigned short* WqT  = (unsigned short*)(ws + off); off += 1048576;   // 512*1024*2
    unsigned short* WkvT = (unsigned short*)(ws + off); off += 2097152;   // 1024*1024*2
    unsigned short* WoT  = (unsigned short*)(ws + off); off += 1048576;   // 1024*512*2
    unsigned short* kvin = (unsigned short*)(ws + off); off += 83886080;  // 128*320*1024*2
    unsigned short* qb   = (unsigned short*)(ws + off); off += 8388608;   // 128*64*512*2
    unsigned short* kb   = (unsigned short*)(ws + off); off += 41943040;  // 128*320*512*2
    unsigned short* vb   = (unsigned short*)(ws + off); off += 41943040;  // 128*512*320*2
    unsigned short* ab   = (unsigned short*)(ws + off); off += 8388608;   // 128*64*512*2

    hipLaunchKernelGGL(mask_kernel,  dim3(1),     dim3(64),  0, stream, mraw, maskN);
    hipLaunchKernelGGL(wprep_kernel, dim3(8192),  dim3(256), 0, stream,
                       Wq, Wkv, Wo, WqT, WkvT, WoT);
    hipLaunchKernelGGL(ln_kernel,    dim3(40960), dim3(256), 0, stream,
                       x, lat, gm, bm, gl, bl, maskN, kvin);
    hipLaunchKernelGGL((gemm128_kernel<0>), dim3(256),  dim3(256), 0, stream,
                       kvin, WqT,  maskN, qb, kb, vb, out);
    hipLaunchKernelGGL((gemm128_kernel<1>), dim3(2560), dim3(256), 0, stream,
                       kvin, WkvT, maskN, qb, kb, vb, out);
    hipLaunchKernelGGL(attn_kernel,         dim3(1024), dim3(256), 0, stream,
                       qb, kb, vb, maskN, ab);
    hipLaunchKernelGGL((gemm128_kernel<2>), dim3(512),  dim3(256), 0, stream,
                       ab, WoT,  maskN, qb, kb, vb, out);
}

// Round 7
// 218.905 us; speedup vs baseline: 1.0942x; 1.0942x over previous
//
#include <hip/hip_runtime.h>
#include <stdint.h>
#include <stddef.h>

#define B_      8
#define T_      16
#define NX_     256
#define NZ_     64
#define D_      1024
#define HEADS_  8
#define DHEAD_  64
#define INNER_  512
#define NKEY_   320          // NX_ + NZ_
#define NBT_    128          // B_*T_

typedef __attribute__((ext_vector_type(8))) short     short8;
typedef __attribute__((ext_vector_type(4))) float     f32x4;
typedef __attribute__((ext_vector_type(8))) unsigned short u16x8;

__device__ __forceinline__ unsigned short f2bf(float f) {
    union { float f; unsigned int u; } v; v.f = f;
    unsigned int u = v.u;
    return (unsigned short)((u + 0x7fffu + ((u >> 16) & 1u)) >> 16);
}

__device__ __forceinline__ void async16(unsigned short* lds, const unsigned short* g) {
    __builtin_amdgcn_global_load_lds(
        (const __attribute__((address_space(1))) void*)g,
        (__attribute__((address_space(3))) void*)lds, 16, 0, 0);
}

// ---------------------------------------------------------------------------
// mask normalization: handles both bool-byte and int32 storage of mask[128]
// ---------------------------------------------------------------------------
__global__ void mask_kernel(const unsigned char* __restrict__ mraw,
                            int* __restrict__ maskN) {
    int lane = threadIdx.x;                 // 64 threads
    unsigned char b0 = mraw[lane];
    unsigned char b1 = mraw[lane + 64];
    bool nz = (((lane) & 3) != 0 && b0 != 0) || (((lane + 64) & 3) != 0 && b1 != 0);
    unsigned long long ball = __ballot(nz ? 1 : 0);
    bool isBool = (ball != 0ull);
    int v0, v1;
    if (isBool) { v0 = b0; v1 = b1; }
    else        { v0 = mraw[4 * lane]; v1 = mraw[4 * (lane + 64)]; }
    maskN[lane]      = v0 ? 1 : 0;
    maskN[lane + 64] = v1 ? 1 : 0;
}

// ---------------------------------------------------------------------------
// weight prep: f32 -> bf16, transposed to [N][K]
// ---------------------------------------------------------------------------
__global__ __launch_bounds__(256) void wprep_kernel(
        const float* __restrict__ Wq, const float* __restrict__ Wkv,
        const float* __restrict__ Wo,
        unsigned short* __restrict__ WqT, unsigned short* __restrict__ WkvT,
        unsigned short* __restrict__ WoT) {
    size_t id = (size_t)blockIdx.x * 256 + threadIdx.x;
    if (id < 524288) {                       // WqT[512][1024] <- Wq[1024][512]
        int n = (int)(id >> 10), k = (int)(id & 1023);
        WqT[id] = f2bf(Wq[(size_t)k * 512 + n]);
    } else if (id < 524288 + 1048576) {      // WkvT[1024][1024] <- Wkv[1024][1024]
        size_t j = id - 524288;
        int n = (int)(j >> 10), k = (int)(j & 1023);
        WkvT[j] = f2bf(Wkv[(size_t)k * 1024 + n]);
    } else {                                 // WoT[1024][512] <- Wo[512][1024]
        size_t j = id - 1572864;
        int n = (int)(j >> 9), k = (int)(j & 511);
        WoT[j] = f2bf(Wo[(size_t)k * 1024 + n]);
    }
}

// ---------------------------------------------------------------------------
// LayerNorm rows of x (32768) and latents (8192) -> bf16 packed kvin
// kvin[bt][0..255][1024] = xn rows, kvin[bt][256..319][1024] = zn rows
// ---------------------------------------------------------------------------
__global__ __launch_bounds__(256) void ln_kernel(
        const float* __restrict__ x, const float* __restrict__ lat,
        const float* __restrict__ gm, const float* __restrict__ bm,
        const float* __restrict__ gl, const float* __restrict__ bl,
        const int* __restrict__ maskN,
        unsigned short* __restrict__ kvin) {
    int row = blockIdx.x;
    const float* src; unsigned short* dst; const float* g; const float* b;
    int bt;
    if (row < NBT_ * NX_) {
        bt = row >> 8;
        src = x + (size_t)row * D_;
        dst = kvin + ((size_t)bt * NKEY_ + (row & 255)) * D_;
        g = gm; b = bm;
    } else {
        int r = row - NBT_ * NX_;
        bt = r >> 6;
        src = lat + (size_t)r * D_;
        dst = kvin + ((size_t)bt * NKEY_ + 256 + (r & 63)) * D_;
        g = gl; b = bl;
    }
    if (!maskN[bt]) return;                  // masked (b,t): values never read
    int t = threadIdx.x;
    float4 v = reinterpret_cast<const float4*>(src)[t];
    float s  = v.x + v.y + v.z + v.w;
    float sq = v.x * v.x + v.y * v.y + v.z * v.z + v.w * v.w;
    #pragma unroll
    for (int off = 32; off > 0; off >>= 1) {
        s  += __shfl_down(s, off);
        sq += __shfl_down(sq, off);
    }
    __shared__ float red[8];
    int wid = t >> 6;
    if ((t & 63) == 0) { red[wid] = s; red[4 + wid] = sq; }
    __syncthreads();
    float stot = red[0] + red[1] + red[2] + red[3];
    float qtot = red[4] + red[5] + red[6] + red[7];
    float mean = stot * (1.0f / 1024.0f);
    float var  = qtot * (1.0f / 1024.0f) - mean * mean;
    float rstd = rsqrtf(var + 1e-5f);
    float4 gv = reinterpret_cast<const float4*>(g)[t];
    float4 bv = reinterpret_cast<const float4*>(b)[t];
    ushort4 o;
    o.x = f2bf((v.x - mean) * rstd * gv.x + bv.x);
    o.y = f2bf((v.y - mean) * rstd * gv.y + bv.y);
    o.z = f2bf((v.z - mean) * rstd * gv.z + bv.z);
    o.w = f2bf((v.w - mean) * rstd * gv.w + bv.w);
    *reinterpret_cast<ushort4*>(dst + 4 * t) = o;
}

// ---------------------------------------------------------------------------
// kv-GEMM, 256x256 tile (m201 geometry), BK=64, 8 waves (2M x 4N), 128KB LDS
// dbuf, R5-proven counted-vmcnt schedule scaled up:
//   per K-tile: issue 8 prefetch gload_lds slices -> vmcnt(8) waits only the
//   PREVIOUS tile's slices (aged one full K-tile) -> barrier -> 64 MFMA/wave
//   compute section (setprio-wrapped) -> lgkmcnt(0) -> barrier.
// C = kvin[40960][1024] @ WkvT^T -> k [bt][320][512], vT [bt][512][320]
// ---------------------------------------------------------------------------
__global__ __launch_bounds__(512) void gemm256_kv(
        const unsigned short* __restrict__ A,
        const unsigned short* __restrict__ BT,
        const int* __restrict__ maskN,
        unsigned short* __restrict__ o_k,
        unsigned short* __restrict__ o_v) {
    constexpr int NSTEP = 16;                  // K=1024 / 64
    // grid = 640 = 160 M-tiles x 4 N-tiles; XCD-chunked swizzle (640/8=80)
    int swz = (blockIdx.x & 7) * 80 + (blockIdx.x >> 3);
    int mt = swz >> 2, nt = swz & 3;
    int m0 = mt * 256, n0 = nt * 256;

    int bt0 = m0 / NKEY_, bt1 = (m0 + 255) / NKEY_;
    bool any = false;
    for (int b = bt0; b <= bt1; b++) any |= (maskN[b] != 0);
    if (!any) return;                          // outputs of dead bt never read

    int t = threadIdx.x;
    int lane = t & 63, w = t >> 6;
    int lr = lane & 15, lg = lane >> 4;
    int wm = w >> 2, wn = w & 3;

    __shared__ __align__(16) unsigned short As[2][16384];   // 2 x 256x64
    __shared__ __align__(16) unsigned short Bs[2][16384];

    // staging: call j covers rows j*64..+64 (8KB, 512 thr x 16B)
    // thread t: row = j*64 + (t>>3), col = k0 + (t&7)*8
    const unsigned short* aSrc = A  + (size_t)(m0 + (t >> 3)) * 1024 + (t & 7) * 8;
    const unsigned short* bSrc = BT + (size_t)(n0 + (t >> 3)) * 1024 + (t & 7) * 8;

    #define STAGE(BUF, K0)                                                    \
        {                                                                     \
            _Pragma("unroll")                                                 \
            for (int j = 0; j < 4; j++)                                       \
                async16(&As[BUF][j * 4096 + w * 512], aSrc + (size_t)j * 65536 + (K0)); \
            _Pragma("unroll")                                                 \
            for (int j = 0; j < 4; j++)                                       \
                async16(&Bs[BUF][j * 4096 + w * 512], bSrc + (size_t)j * 65536 + (K0)); \
        }

    f32x4 acc[8][4];
    #pragma unroll
    for (int i = 0; i < 8; i++)
        #pragma unroll
        for (int j = 0; j < 4; j++) acc[i][j] = (f32x4){0.f, 0.f, 0.f, 0.f};

    #define COMPUTE(BUF)                                                      \
        {                                                                     \
            _Pragma("unroll")                                                 \
            for (int kc = 0; kc < 2; kc++) {                                  \
                short8 bf[4];                                                 \
                _Pragma("unroll")                                             \
                for (int ni = 0; ni < 4; ni++)                                \
                    bf[ni] = *reinterpret_cast<const short8*>(                \
                        &Bs[BUF][(wn * 64 + ni * 16 + lr) * 64 + kc * 32 + lg * 8]); \
                _Pragma("unroll")                                             \
                for (int mh = 0; mh < 2; mh++) {                              \
                    short8 af[4];                                             \
                    _Pragma("unroll")                                         \
                    for (int mi = 0; mi < 4; mi++)                            \
                        af[mi] = *reinterpret_cast<const short8*>(            \
                            &As[BUF][(wm * 128 + mh * 64 + mi * 16 + lr) * 64 + kc * 32 + lg * 8]); \
                    _Pragma("unroll")                                         \
                    for (int mi = 0; mi < 4; mi++)                            \
                        _Pragma("unroll")                                     \
                        for (int ni = 0; ni < 4; ni++)                        \
                            acc[mh * 4 + mi][ni] = __builtin_amdgcn_mfma_f32_16x16x32_bf16( \
                                af[mi], bf[ni], acc[mh * 4 + mi][ni], 0, 0, 0); \
                }                                                             \
            }                                                                 \
        }

    #define KSTEP(CUR, NEXTK0)                                               \
        STAGE((CUR) ^ 1, NEXTK0)                                             \
        asm volatile("s_waitcnt vmcnt(8)" ::: "memory");                     \
        __builtin_amdgcn_s_barrier();                                        \
        __builtin_amdgcn_s_setprio(1);                                       \
        COMPUTE(CUR)                                                         \
        __builtin_amdgcn_s_setprio(0);                                       \
        asm volatile("s_waitcnt lgkmcnt(0)" ::: "memory");                   \
        __builtin_amdgcn_sched_barrier(0);                                   \
        __builtin_amdgcn_s_barrier();

    STAGE(0, 0)                                // prologue: tile 0 in flight
    #pragma unroll 1
    for (int ks2 = 0; ks2 < NSTEP / 2 - 1; ks2++) {
        int k0a = (2 * ks2 + 1) * 64, k0b = (2 * ks2 + 2) * 64;
        KSTEP(0, k0a)                          // tile 2k, stages 2k+1
        KSTEP(1, k0b)                          // tile 2k+1, stages 2k+2
    }
    KSTEP(0, (NSTEP - 1) * 64)                 // tile 14, stages tile 15
    asm volatile("s_waitcnt vmcnt(0)" ::: "memory");
    __builtin_amdgcn_s_barrier();
    COMPUTE(1)                                 // tile 15
    #undef KSTEP
    #undef COMPUTE
    #undef STAGE

    // epilogue: k cols <512 -> o_k rows; cols >=512 -> vT packed 4-row stores
    #pragma unroll
    for (int mi = 0; mi < 8; mi++)
        #pragma unroll
        for (int ni = 0; ni < 4; ni++) {
            int gr0 = m0 + wm * 128 + mi * 16 + lg * 4;    // 4 rows, same bt
            int c   = n0 + wn * 64 + ni * 16 + lr;
            int bt  = gr0 / NKEY_;
            int krow = gr0 - bt * NKEY_;
            if (c < 512) {
                #pragma unroll
                for (int r = 0; r < 4; r++)
                    o_k[((size_t)bt * NKEY_ + krow + r) * 512 + c] = f2bf(acc[mi][ni][r]);
            } else {
                ushort4 pv;
                pv.x = f2bf(acc[mi][ni][0]); pv.y = f2bf(acc[mi][ni][1]);
                pv.z = f2bf(acc[mi][ni][2]); pv.w = f2bf(acc[mi][ni][3]);
                *reinterpret_cast<ushort4*>(
                    o_v + ((size_t)bt * 512 + (c - 512)) * NKEY_ + krow) = pv;
            }
        }
}

// ---------------------------------------------------------------------------
// 2-phase dbuf GEMM with COUNTED vmcnt (R5 structure): 128x128, 4 waves.
// MODE 0: q  [8192][512]  = kvin-z rows @ WqT,  *0.125, bf16
// MODE 2: out[8192][1024] = ao @ WoT, f32, zeros for masked rows
// ---------------------------------------------------------------------------
template<int MODE>
__global__ __launch_bounds__(256) void gemm128_kernel(
        const unsigned short* __restrict__ A,
        const unsigned short* __restrict__ BT,
        const int* __restrict__ maskN,
        unsigned short* __restrict__ o_q,
        float* __restrict__ o_f) {
    constexpr int K     = (MODE == 2) ? 512 : 1024;
    constexpr int NSTEP = K / 64;
    constexpr int NT    = (MODE == 0) ? 4 : 8;                 // N-tiles
    constexpr int CHUNK = (MODE == 0) ? 32 : 64;

    int swz = (blockIdx.x & 7) * CHUNK + (blockIdx.x >> 3);    // XCD-chunked
    int nt = swz % NT, mt = swz / NT;
    int m0 = mt * 128, n0 = nt * 128;
    int t = threadIdx.x;
    int lane = t & 63, wid = t >> 6;
    int lr = lane & 15, lg = lane >> 4;
    int wm = wid >> 1, wn = wid & 1;

    int bt0 = m0 >> 6, bt1 = bt0 + 1;
    bool any = (maskN[bt0] != 0) || (maskN[bt1] != 0);
    if (!any) {
        if (MODE == 2) {                       // masked out rows must be zero
            int r = t >> 1, cb = (t & 1) * 64;
            float4 z = make_float4(0.f, 0.f, 0.f, 0.f);
            float4* p = reinterpret_cast<float4*>(o_f + (size_t)(m0 + r) * 1024 + n0 + cb);
            #pragma unroll
            for (int j = 0; j < 16; j++) p[j] = z;
        }
        return;
    }

    __shared__ __align__(16) unsigned short As[2][8192];   // 2 x 128x64
    __shared__ __align__(16) unsigned short Bs[2][8192];

    const unsigned short* aptr[4];
    const unsigned short* bptr[4];
    #pragma unroll
    for (int i = 0; i < 4; i++) {
        int row = m0 + wid * 32 + i * 8 + (lane >> 3);
        size_t srow;
        if (MODE == 0) { int bt = row >> 6; srow = (size_t)bt * NKEY_ + 256 + (row & 63); }
        else           srow = (size_t)row;
        aptr[i] = A  + srow * K + (lane & 7) * 8;
        int brow = n0 + wid * 32 + i * 8 + (lane >> 3);
        bptr[i] = BT + (size_t)brow * K + (lane & 7) * 8;
    }

    f32x4 acc[4][4];
    #pragma unroll
    for (int i = 0; i < 4; i++)
        #pragma unroll
        for (int j = 0; j < 4; j++) acc[i][j] = (f32x4){0.f, 0.f, 0.f, 0.f};

    auto stage = [&](int buf) {
        unsigned short* as = &As[buf][wid * 2048];
        unsigned short* bs = &Bs[buf][wid * 2048];
        #pragma unroll
        for (int i = 0; i < 4; i++) {
            async16(as + i * 512, aptr[i]);
            async16(bs + i * 512, bptr[i]);
            aptr[i] += 64; bptr[i] += 64;
        }
    };
    auto compute = [&](int buf) {
        #pragma unroll
        for (int kc = 0; kc < 2; kc++) {
            short8 af[4], bf[4];
            #pragma unroll
            for (int mi = 0; mi < 4; mi++)
                af[mi] = *reinterpret_cast<const short8*>(
                    &As[buf][(wm * 64 + mi * 16 + lr) * 64 + kc * 32 + lg * 8]);
            #pragma unroll
            for (int ni = 0; ni < 4; ni++)
                bf[ni] = *reinterpret_cast<const short8*>(
                    &Bs[buf][(wn * 64 + ni * 16 + lr) * 64 + kc * 32 + lg * 8]);
            #pragma unroll
            for (int mi = 0; mi < 4; mi++)
                #pragma unroll
                for (int ni = 0; ni < 4; ni++)
                    acc[mi][ni] = __builtin_amdgcn_mfma_f32_16x16x32_bf16(
                        af[mi], bf[ni], acc[mi][ni], 0, 0, 0);
        }
    };

    #define FULL_STEP(CUR)                                              \
        stage((CUR) ^ 1);                                               \
        asm volatile("s_waitcnt vmcnt(8)" ::: "memory");                \
        __builtin_amdgcn_s_barrier();                                   \
        compute(CUR);                                                   \
        asm volatile("s_waitcnt lgkmcnt(0)" ::: "memory");              \
        __builtin_amdgcn_s_barrier();

    stage(0);
    #pragma unroll 1
    for (int ks2 = 0; ks2 < NSTEP / 2 - 1; ks2++) {
        FULL_STEP(0)
        FULL_STEP(1)
    }
    FULL_STEP(0)
    asm volatile("s_waitcnt vmcnt(0)" ::: "memory");
    __builtin_amdgcn_s_barrier();
    compute(1);
    #undef FULL_STEP

    #pragma unroll
    for (int mi = 0; mi < 4; mi++)
        #pragma unroll
        for (int ni = 0; ni < 4; ni++) {
            int gr0 = m0 + wm * 64 + mi * 16 + lg * 4;
            int c   = n0 + wn * 64 + ni * 16 + lr;
            if (MODE == 0) {
                #pragma unroll
                for (int r = 0; r < 4; r++)
                    o_q[(size_t)(gr0 + r) * 512 + c] = f2bf(acc[mi][ni][r] * 0.125f);
            } else {
                int bt = gr0 >> 6;
                bool live = maskN[bt] != 0;
                #pragma unroll
                for (int r = 0; r < 4; r++)
                    o_f[(size_t)(gr0 + r) * 1024 + c] = live ? acc[mi][ni][r] : 0.0f;
            }
        }
}

// ---------------------------------------------------------------------------
// fused attention per (b,t,h): sim = q @ k^T (64x320), softmax, out = attn @ v
// ---------------------------------------------------------------------------
__global__ __launch_bounds__(256) void attn_kernel(
        const unsigned short* __restrict__ q,
        const unsigned short* __restrict__ kbuf,
        const unsigned short* __restrict__ vbuf,   // vT [bt][512][320]
        const int* __restrict__ maskN,
        unsigned short* __restrict__ ao) {
    const int nwg = gridDim.x;                     // 1024
    int bid = (blockIdx.x & 7) * (nwg >> 3) + (blockIdx.x >> 3);
    int bt = bid >> 3, h = bid & 7;
    if (!maskN[bt]) return;
    int t = threadIdx.x, w = t >> 6, lane = t & 63;
    int lr = lane & 15, lg = lane >> 4;
    __shared__ __align__(16) unsigned short attn_s[4][16][328];

    const unsigned short* qrow = q + ((size_t)bt * 64 + w * 16 + lr) * 512 + h * 64;
    short8 qa0 = *reinterpret_cast<const short8*>(qrow + lg * 8);
    short8 qa1 = *reinterpret_cast<const short8*>(qrow + 32 + lg * 8);

    f32x4 acc[20];
    #pragma unroll
    for (int i = 0; i < 20; i++) acc[i] = (f32x4){0.f, 0.f, 0.f, 0.f};

    const unsigned short* kb = kbuf + (size_t)bt * NKEY_ * 512 + h * 64;
    #pragma unroll
    for (int nt2 = 0; nt2 < 20; nt2++) {
        const unsigned short* krow = kb + (size_t)(nt2 * 16 + lr) * 512;
        short8 b0 = *reinterpret_cast<const short8*>(krow + lg * 8);
        short8 b1 = *reinterpret_cast<const short8*>(krow + 32 + lg * 8);
        acc[nt2] = __builtin_amdgcn_mfma_f32_16x16x32_bf16(qa0, b0, acc[nt2], 0, 0, 0);
        acc[nt2] = __builtin_amdgcn_mfma_f32_16x16x32_bf16(qa1, b1, acc[nt2], 0, 0, 0);
    }

    float mx[4], sm[4];
    #pragma unroll
    for (int r = 0; r < 4; r++) mx[r] = -1e30f;
    #pragma unroll
    for (int nt2 = 0; nt2 < 20; nt2++)
        #pragma unroll
        for (int r = 0; r < 4; r++) mx[r] = fmaxf(mx[r], acc[nt2][r]);
    #pragma unroll
    for (int r = 0; r < 4; r++) {
        #pragma unroll
        for (int off = 1; off < 16; off <<= 1)
            mx[r] = fmaxf(mx[r], __shfl_xor(mx[r], off));
        sm[r] = 0.f;
    }
    #pragma unroll
    for (int nt2 = 0; nt2 < 20; nt2++)
        #pragma unroll
        for (int r = 0; r < 4; r++) {
            float p = __expf(acc[nt2][r] - mx[r]);
            acc[nt2][r] = p;
            sm[r] += p;
        }
    #pragma unroll
    for (int r = 0; r < 4; r++) {
        #pragma unroll
        for (int off = 1; off < 16; off <<= 1)
            sm[r] += __shfl_xor(sm[r], off);
        sm[r] = 1.0f / sm[r];
    }
    #pragma unroll
    for (int nt2 = 0; nt2 < 20; nt2++)
        #pragma unroll
        for (int r = 0; r < 4; r++)
            attn_s[w][lg * 4 + r][nt2 * 16 + lr] = f2bf(acc[nt2][r] * sm[r]);
    __syncthreads();

    f32x4 o[4];
    #pragma unroll
    for (int i = 0; i < 4; i++) o[i] = (f32x4){0.f, 0.f, 0.f, 0.f};
    const unsigned short* vb = vbuf + (size_t)bt * 512 * NKEY_ + (size_t)h * 64 * NKEY_;
    #pragma unroll
    for (int kc = 0; kc < 10; kc++) {
        short8 pa = *reinterpret_cast<const short8*>(&attn_s[w][lr][kc * 32 + lg * 8]);
        #pragma unroll
        for (int ni = 0; ni < 4; ni++) {
            short8 vf = *reinterpret_cast<const short8*>(
                vb + (size_t)(ni * 16 + lr) * NKEY_ + kc * 32 + lg * 8);
            o[ni] = __builtin_amdgcn_mfma_f32_16x16x32_bf16(pa, vf, o[ni], 0, 0, 0);
        }
    }
    #pragma unroll
    for (int ni = 0; ni < 4; ni++)
        #pragma unroll
        for (int r = 0; r < 4; r++)
            ao[((size_t)bt * 64 + w * 16 + lg * 4 + r) * 512 + h * 64 + ni * 16 + lr] =
                f2bf(o[ni][r]);
}

// ---------------------------------------------------------------------------
extern "C" void kernel_launch(void* const* d_in, const int* in_sizes, int n_in,
                              void* d_out, int out_size, void* d_ws, size_t ws_size,
                              hipStream_t stream) {
    const float* x            = (const float*)d_in[0];
    const float* lat          = (const float*)d_in[1];
    const unsigned char* mraw = (const unsigned char*)d_in[2];
    const float* gm           = (const float*)d_in[3];
    const float* bm           = (const float*)d_in[4];
    const float* gl           = (const float*)d_in[5];
    const float* bl           = (const float*)d_in[6];
    const float* Wq           = (const float*)d_in[7];
    const float* Wkv          = (const float*)d_in[8];
    const float* Wo           = (const float*)d_in[9];
    float* out = (float*)d_out;

    char* ws = (char*)d_ws;
    size_t off = 0;
    int* maskN = (int*)(ws + off);             off += 1024;
    unsigned short* WqT  = (unsigned short*)(ws + off); off += 1048576;   // 512*1024*2
    unsigned short* WkvT = (unsigned short*)(ws + off); off += 2097152;   // 1024*1024*2
    unsigned short* WoT  = (unsigned short*)(ws + off); off += 1048576;   // 1024*512*2
    unsigned short* kvin = (unsigned short*)(ws + off); off += 83886080;  // 128*320*1024*2
    unsigned short* qb   = (unsigned short*)(ws + off); off += 8388608;   // 128*64*512*2
    unsigned short* kb   = (unsigned short*)(ws + off); off += 41943040;  // 128*320*512*2
    unsigned short* vb   = (unsigned short*)(ws + off); off += 41943040;  // 128*512*320*2
    unsigned short* ab   = (unsigned short*)(ws + off); off += 8388608;   // 128*64*512*2

    hipLaunchKernelGGL(mask_kernel,  dim3(1),     dim3(64),  0, stream, mraw, maskN);
    hipLaunchKernelGGL(wprep_kernel, dim3(8192),  dim3(256), 0, stream,
                       Wq, Wkv, Wo, WqT, WkvT, WoT);
    hipLaunchKernelGGL(ln_kernel,    dim3(40960), dim3(256), 0, stream,
                       x, lat, gm, bm, gl, bl, maskN, kvin);
    hipLaunchKernelGGL((gemm128_kernel<0>), dim3(256),  dim3(256), 0, stream,
                       kvin, WqT,  maskN, qb, out);
    hipLaunchKernelGGL(gemm256_kv,          dim3(640),  dim3(512), 0, stream,
                       kvin, WkvT, maskN, kb, vb);
    hipLaunchKernelGGL(attn_kernel,         dim3(1024), dim3(256), 0, stream,
                       qb, kb, vb, maskN, ab);
    hipLaunchKernelGGL((gemm128_kernel<2>), dim3(512),  dim3(256), 0, stream,
                       ab, WoT,  maskN, qb, out);
}

// Round 8
// 195.286 us; speedup vs baseline: 1.2266x; 1.1209x over previous
//
#include <hip/hip_runtime.h>
#include <stdint.h>
#include <stddef.h>

#define B_      8
#define T_      16
#define NX_     256
#define NZ_     64
#define D_      1024
#define HEADS_  8
#define DHEAD_  64
#define INNER_  512
#define NKEY_   320          // NX_ + NZ_
#define NBT_    128          // B_*T_

typedef __attribute__((ext_vector_type(8))) short     short8;
typedef __attribute__((ext_vector_type(4))) float     f32x4;
typedef __attribute__((ext_vector_type(8))) unsigned short u16x8;

__device__ __forceinline__ unsigned short f2bf(float f) {
    union { float f; unsigned int u; } v; v.f = f;
    unsigned int u = v.u;
    return (unsigned short)((u + 0x7fffu + ((u >> 16) & 1u)) >> 16);
}

__device__ __forceinline__ void async16(unsigned short* lds, const unsigned short* g) {
    __builtin_amdgcn_global_load_lds(
        (const __attribute__((address_space(1))) void*)g,
        (__attribute__((address_space(3))) void*)lds, 16, 0, 0);
}

// ---------------------------------------------------------------------------
// mask normalization + live-compaction lists.
// meta[0]=nliveBt, meta[1]=#kv M-tiles (live-64-row-group pairs),
// meta[2]=#bt-pair tiles for q/out GEMMs.
// grpSrc[g] = kvin row base of live 64-row group g; grpOut[g]=(bt<<16)|krow0.
// ---------------------------------------------------------------------------
__global__ void mask_kernel(const unsigned char* __restrict__ mraw,
                            int* __restrict__ maskN, int* __restrict__ meta,
                            int* __restrict__ liveBt, int* __restrict__ grpSrc,
                            int* __restrict__ grpOut) {
    int lane = threadIdx.x;                 // 64 threads
    unsigned char b0 = mraw[lane];
    unsigned char b1 = mraw[lane + 64];
    bool nz = (((lane) & 3) != 0 && b0 != 0) || (((lane + 64) & 3) != 0 && b1 != 0);
    unsigned long long ball = __ballot(nz ? 1 : 0);
    bool isBool = (ball != 0ull);
    int v0, v1;
    if (isBool) { v0 = b0; v1 = b1; }
    else        { v0 = mraw[4 * lane]; v1 = mraw[4 * (lane + 64)]; }
    maskN[lane]      = v0 ? 1 : 0;
    maskN[lane + 64] = v1 ? 1 : 0;
    __syncthreads();
    if (lane == 0) {
        int nl = 0, ng = 0;
        for (int bt = 0; bt < NBT_; bt++) {
            if (maskN[bt]) {
                liveBt[nl++] = bt;
                #pragma unroll
                for (int g = 0; g < 5; g++) {
                    grpSrc[ng] = bt * NKEY_ + g * 64;
                    grpOut[ng] = (bt << 16) | (g * 64);
                    ng++;
                }
            }
        }
        if (nl & 1) liveBt[nl] = nl ? liveBt[nl - 1] : 0;
        if (ng & 1) { grpSrc[ng] = ng ? grpSrc[ng - 1] : 0;
                      grpOut[ng] = ng ? grpOut[ng - 1] : 0; }
        meta[0] = nl;
        meta[1] = (ng + 1) >> 1;
        meta[2] = (nl + 1) >> 1;
    }
}

// ---------------------------------------------------------------------------
// weight prep: f32 -> bf16, transposed to [N][K]
// ---------------------------------------------------------------------------
__global__ __launch_bounds__(256) void wprep_kernel(
        const float* __restrict__ Wq, const float* __restrict__ Wkv,
        const float* __restrict__ Wo,
        unsigned short* __restrict__ WqT, unsigned short* __restrict__ WkvT,
        unsigned short* __restrict__ WoT) {
    size_t id = (size_t)blockIdx.x * 256 + threadIdx.x;
    if (id < 524288) {                       // WqT[512][1024] <- Wq[1024][512]
        int n = (int)(id >> 10), k = (int)(id & 1023);
        WqT[id] = f2bf(Wq[(size_t)k * 512 + n]);
    } else if (id < 524288 + 1048576) {      // WkvT[1024][1024] <- Wkv[1024][1024]
        size_t j = id - 524288;
        int n = (int)(j >> 10), k = (int)(j & 1023);
        WkvT[j] = f2bf(Wkv[(size_t)k * 1024 + n]);
    } else {                                 // WoT[1024][512] <- Wo[512][1024]
        size_t j = id - 1572864;
        int n = (int)(j >> 9), k = (int)(j & 511);
        WoT[j] = f2bf(Wo[(size_t)k * 1024 + n]);
    }
}

// ---------------------------------------------------------------------------
// LayerNorm rows of x (32768) and latents (8192) -> bf16 packed kvin
// ---------------------------------------------------------------------------
__global__ __launch_bounds__(256) void ln_kernel(
        const float* __restrict__ x, const float* __restrict__ lat,
        const float* __restrict__ gm, const float* __restrict__ bm,
        const float* __restrict__ gl, const float* __restrict__ bl,
        const int* __restrict__ maskN,
        unsigned short* __restrict__ kvin) {
    int row = blockIdx.x;
    const float* src; unsigned short* dst; const float* g; const float* b;
    int bt;
    if (row < NBT_ * NX_) {
        bt = row >> 8;
        src = x + (size_t)row * D_;
        dst = kvin + ((size_t)bt * NKEY_ + (row & 255)) * D_;
        g = gm; b = bm;
    } else {
        int r = row - NBT_ * NX_;
        bt = r >> 6;
        src = lat + (size_t)r * D_;
        dst = kvin + ((size_t)bt * NKEY_ + 256 + (r & 63)) * D_;
        g = gl; b = bl;
    }
    if (!maskN[bt]) return;                  // masked (b,t): values never read
    int t = threadIdx.x;
    float4 v = reinterpret_cast<const float4*>(src)[t];
    float s  = v.x + v.y + v.z + v.w;
    float sq = v.x * v.x + v.y * v.y + v.z * v.z + v.w * v.w;
    #pragma unroll
    for (int off = 32; off > 0; off >>= 1) {
        s  += __shfl_down(s, off);
        sq += __shfl_down(sq, off);
    }
    __shared__ float red[8];
    int wid = t >> 6;
    if ((t & 63) == 0) { red[wid] = s; red[4 + wid] = sq; }
    __syncthreads();
    float stot = red[0] + red[1] + red[2] + red[3];
    float qtot = red[4] + red[5] + red[6] + red[7];
    float mean = stot * (1.0f / 1024.0f);
    float var  = qtot * (1.0f / 1024.0f) - mean * mean;
    float rstd = rsqrtf(var + 1e-5f);
    float4 gv = reinterpret_cast<const float4*>(g)[t];
    float4 bv = reinterpret_cast<const float4*>(b)[t];
    ushort4 o;
    o.x = f2bf((v.x - mean) * rstd * gv.x + bv.x);
    o.y = f2bf((v.y - mean) * rstd * gv.y + bv.y);
    o.z = f2bf((v.z - mean) * rstd * gv.z + bv.z);
    o.w = f2bf((v.w - mean) * rstd * gv.w + bv.w);
    *reinterpret_cast<ushort4*>(dst + 4 * t) = o;
}

// ---------------------------------------------------------------------------
// Compacted 2-phase dbuf GEMM (R5-proven schedule): 128x128, BK=64, 4 waves,
// counted vmcnt(8), one raw barrier pair per K-step. M-rows remapped through
// live-compaction lists (no dead-row compute, uniform load balance).
// MODE 0: q  = zn(live) @ WqT,  *0.125, bf16.  grid 4*meta[2] max 256
// MODE 1: kv = kvin(live grps) @ WkvT -> k[bt][320][512], vT[bt][512][320].
//              grid 8*meta[1] max 2560
// MODE 2: out = ao(live) @ WoT, f32 (live rows only). grid 8*meta[2] max 512
// ---------------------------------------------------------------------------
template<int MODE>
__global__ __launch_bounds__(256) void gemm128_kernel(
        const unsigned short* __restrict__ A,
        const unsigned short* __restrict__ BT,
        const int* __restrict__ meta,
        const int* __restrict__ liveBt,
        const int* __restrict__ grpSrc,
        const int* __restrict__ grpOut,
        unsigned short* __restrict__ o_q,
        unsigned short* __restrict__ o_k,
        unsigned short* __restrict__ o_v,
        float* __restrict__ o_f) {
    constexpr int K     = (MODE == 2) ? 512 : 1024;
    constexpr int NSTEP = K / 64;
    constexpr int NTSH  = (MODE == 0) ? 2 : 3;                 // log2(N-tiles)

    int mt = blockIdx.x >> NTSH;
    int nt = blockIdx.x & ((1 << NTSH) - 1);
    int lim = (MODE == 1) ? meta[1] : meta[2];
    if (mt >= lim) return;
    int n0 = nt * 128;
    int t = threadIdx.x;
    int lane = t & 63, wid = t >> 6;
    int lr = lane & 15, lg = lane >> 4;
    int wm = wid >> 1, wn = wid & 1;

    __shared__ __align__(16) unsigned short As[2][8192];   // 2 x 128x64
    __shared__ __align__(16) unsigned short Bs[2][8192];

    // per-lane global staging pointers through compaction maps
    const unsigned short* aptr[4];
    const unsigned short* bptr[4];
    #pragma unroll
    for (int i = 0; i < 4; i++) {
        int r128 = wid * 32 + i * 8 + (lane >> 3);         // 0..127, 8-row
        size_t srow;                                       // slices stay in-group
        if (MODE == 0) {
            int bt = liveBt[2 * mt + (r128 >> 6)];
            srow = (size_t)bt * NKEY_ + 256 + (r128 & 63);
        } else if (MODE == 1) {
            srow = (size_t)grpSrc[2 * mt + (r128 >> 6)] + (r128 & 63);
        } else {
            int bt = liveBt[2 * mt + (r128 >> 6)];
            srow = (size_t)bt * 64 + (r128 & 63);
        }
        aptr[i] = A + srow * K + (lane & 7) * 8;
        int brow = n0 + wid * 32 + i * 8 + (lane >> 3);
        bptr[i] = BT + (size_t)brow * K + (lane & 7) * 8;
    }

    f32x4 acc[4][4];
    #pragma unroll
    for (int i = 0; i < 4; i++)
        #pragma unroll
        for (int j = 0; j < 4; j++) acc[i][j] = (f32x4){0.f, 0.f, 0.f, 0.f};

    auto stage = [&](int buf) {
        unsigned short* as = &As[buf][wid * 2048];
        unsigned short* bs = &Bs[buf][wid * 2048];
        #pragma unroll
        for (int i = 0; i < 4; i++) {
            async16(as + i * 512, aptr[i]);
            async16(bs + i * 512, bptr[i]);
            aptr[i] += 64; bptr[i] += 64;
        }
    };
    auto compute = [&](int buf) {
        #pragma unroll
        for (int kc = 0; kc < 2; kc++) {
            short8 af[4], bf[4];
            #pragma unroll
            for (int mi = 0; mi < 4; mi++)
                af[mi] = *reinterpret_cast<const short8*>(
                    &As[buf][(wm * 64 + mi * 16 + lr) * 64 + kc * 32 + lg * 8]);
            #pragma unroll
            for (int ni = 0; ni < 4; ni++)
                bf[ni] = *reinterpret_cast<const short8*>(
                    &Bs[buf][(wn * 64 + ni * 16 + lr) * 64 + kc * 32 + lg * 8]);
            #pragma unroll
            for (int mi = 0; mi < 4; mi++)
                #pragma unroll
                for (int ni = 0; ni < 4; ni++)
                    acc[mi][ni] = __builtin_amdgcn_mfma_f32_16x16x32_bf16(
                        af[mi], bf[ni], acc[mi][ni], 0, 0, 0);
        }
    };

    #define FULL_STEP(CUR)                                              \
        stage((CUR) ^ 1);                                               \
        asm volatile("s_waitcnt vmcnt(8)" ::: "memory");                \
        __builtin_amdgcn_s_barrier();                                   \
        compute(CUR);                                                   \
        asm volatile("s_waitcnt lgkmcnt(0)" ::: "memory");              \
        __builtin_amdgcn_s_barrier();

    stage(0);
    #pragma unroll 1
    for (int ks2 = 0; ks2 < NSTEP / 2 - 1; ks2++) {
        FULL_STEP(0)
        FULL_STEP(1)
    }
    FULL_STEP(0)
    asm volatile("s_waitcnt vmcnt(0)" ::: "memory");
    __builtin_amdgcn_s_barrier();
    compute(1);
    #undef FULL_STEP

    #pragma unroll
    for (int mi = 0; mi < 4; mi++)
        #pragma unroll
        for (int ni = 0; ni < 4; ni++) {
            int rr = mi * 16 + lg * 4;                     // row in 64-group
            int c  = n0 + wn * 64 + ni * 16 + lr;
            if (MODE == 0) {
                int bt = liveBt[2 * mt + wm];
                #pragma unroll
                for (int r = 0; r < 4; r++)
                    o_q[((size_t)bt * 64 + rr + r) * 512 + c] =
                        f2bf(acc[mi][ni][r] * 0.125f);
            } else if (MODE == 1) {
                int enc = grpOut[2 * mt + wm];
                int bt = enc >> 16, krow = (enc & 0xffff) + rr;
                if (c < 512) {
                    #pragma unroll
                    for (int r = 0; r < 4; r++)
                        o_k[((size_t)bt * NKEY_ + krow + r) * 512 + c] =
                            f2bf(acc[mi][ni][r]);
                } else {
                    ushort4 pv;
                    pv.x = f2bf(acc[mi][ni][0]); pv.y = f2bf(acc[mi][ni][1]);
                    pv.z = f2bf(acc[mi][ni][2]); pv.w = f2bf(acc[mi][ni][3]);
                    *reinterpret_cast<ushort4*>(
                        o_v + ((size_t)bt * 512 + (c - 512)) * NKEY_ + krow) = pv;
                }
            } else {
                int bt = liveBt[2 * mt + wm];
                #pragma unroll
                for (int r = 0; r < 4; r++)
                    o_f[((size_t)bt * 64 + rr + r) * 1024 + c] = acc[mi][ni][r];
            }
        }
}

// ---------------------------------------------------------------------------
// zero-fill d_out rows of masked (b,t)
// ---------------------------------------------------------------------------
__global__ __launch_bounds__(256) void zero_kernel(const int* __restrict__ maskN,
                                                   float* __restrict__ out) {
    int bt = blockIdx.x;
    if (maskN[bt]) return;
    float4* p = reinterpret_cast<float4*>(out + (size_t)bt * 65536);
    float4 z = make_float4(0.f, 0.f, 0.f, 0.f);
    #pragma unroll
    for (int k = 0; k < 64; k++) p[k * 256 + threadIdx.x] = z;
}

// ---------------------------------------------------------------------------
// fused attention per live (bt,h): sim = q @ k^T (64x320), softmax, attn @ v
// ---------------------------------------------------------------------------
__global__ __launch_bounds__(256) void attn_kernel(
        const unsigned short* __restrict__ q,
        const unsigned short* __restrict__ kbuf,
        const unsigned short* __restrict__ vbuf,   // vT [bt][512][320]
        const int* __restrict__ meta,
        const int* __restrict__ liveBt,
        unsigned short* __restrict__ ao) {
    int i = blockIdx.x >> 3, h = blockIdx.x & 7;
    if (i >= meta[0]) return;
    int bt = liveBt[i];
    int t = threadIdx.x, w = t >> 6, lane = t & 63;
    int lr = lane & 15, lg = lane >> 4;
    __shared__ __align__(16) unsigned short attn_s[4][16][328];

    const unsigned short* qrow = q + ((size_t)bt * 64 + w * 16 + lr) * 512 + h * 64;
    short8 qa0 = *reinterpret_cast<const short8*>(qrow + lg * 8);
    short8 qa1 = *reinterpret_cast<const short8*>(qrow + 32 + lg * 8);

    f32x4 acc[20];
    #pragma unroll
    for (int i2 = 0; i2 < 20; i2++) acc[i2] = (f32x4){0.f, 0.f, 0.f, 0.f};

    const unsigned short* kb = kbuf + (size_t)bt * NKEY_ * 512 + h * 64;
    #pragma unroll
    for (int nt2 = 0; nt2 < 20; nt2++) {
        const unsigned short* krow = kb + (size_t)(nt2 * 16 + lr) * 512;
        short8 b0 = *reinterpret_cast<const short8*>(krow + lg * 8);
        short8 b1 = *reinterpret_cast<const short8*>(krow + 32 + lg * 8);
        acc[nt2] = __builtin_amdgcn_mfma_f32_16x16x32_bf16(qa0, b0, acc[nt2], 0, 0, 0);
        acc[nt2] = __builtin_amdgcn_mfma_f32_16x16x32_bf16(qa1, b1, acc[nt2], 0, 0, 0);
    }

    float mx[4], sm[4];
    #pragma unroll
    for (int r = 0; r < 4; r++) mx[r] = -1e30f;
    #pragma unroll
    for (int nt2 = 0; nt2 < 20; nt2++)
        #pragma unroll
        for (int r = 0; r < 4; r++) mx[r] = fmaxf(mx[r], acc[nt2][r]);
    #pragma unroll
    for (int r = 0; r < 4; r++) {
        #pragma unroll
        for (int off = 1; off < 16; off <<= 1)
            mx[r] = fmaxf(mx[r], __shfl_xor(mx[r], off));
        sm[r] = 0.f;
    }
    #pragma unroll
    for (int nt2 = 0; nt2 < 20; nt2++)
        #pragma unroll
        for (int r = 0; r < 4; r++) {
            float p = __expf(acc[nt2][r] - mx[r]);
            acc[nt2][r] = p;
            sm[r] += p;
        }
    #pragma unroll
    for (int r = 0; r < 4; r++) {
        #pragma unroll
        for (int off = 1; off < 16; off <<= 1)
            sm[r] += __shfl_xor(sm[r], off);
        sm[r] = 1.0f / sm[r];
    }
    #pragma unroll
    for (int nt2 = 0; nt2 < 20; nt2++)
        #pragma unroll
        for (int r = 0; r < 4; r++)
            attn_s[w][lg * 4 + r][nt2 * 16 + lr] = f2bf(acc[nt2][r] * sm[r]);
    __syncthreads();

    f32x4 o[4];
    #pragma unroll
    for (int i2 = 0; i2 < 4; i2++) o[i2] = (f32x4){0.f, 0.f, 0.f, 0.f};
    const unsigned short* vb = vbuf + (size_t)bt * 512 * NKEY_ + (size_t)h * 64 * NKEY_;
    #pragma unroll
    for (int kc = 0; kc < 10; kc++) {
        short8 pa = *reinterpret_cast<const short8*>(&attn_s[w][lr][kc * 32 + lg * 8]);
        #pragma unroll
        for (int ni = 0; ni < 4; ni++) {
            short8 vf = *reinterpret_cast<const short8*>(
                vb + (size_t)(ni * 16 + lr) * NKEY_ + kc * 32 + lg * 8);
            o[ni] = __builtin_amdgcn_mfma_f32_16x16x32_bf16(pa, vf, o[ni], 0, 0, 0);
        }
    }
    #pragma unroll
    for (int ni = 0; ni < 4; ni++)
        #pragma unroll
        for (int r = 0; r < 4; r++)
            ao[((size_t)bt * 64 + w * 16 + lg * 4 + r) * 512 + h * 64 + ni * 16 + lr] =
                f2bf(o[ni][r]);
}

// ---------------------------------------------------------------------------
extern "C" void kernel_launch(void* const* d_in, const int* in_sizes, int n_in,
                              void* d_out, int out_size, void* d_ws, size_t ws_size,
                              hipStream_t stream) {
    const float* x            = (const float*)d_in[0];
    const float* lat          = (const float*)d_in[1];
    const unsigned char* mraw = (const unsigned char*)d_in[2];
    const float* gm           = (const float*)d_in[3];
    const float* bm           = (const float*)d_in[4];
    const float* gl           = (const float*)d_in[5];
    const float* bl           = (const float*)d_in[6];
    const float* Wq           = (const float*)d_in[7];
    const float* Wkv          = (const float*)d_in[8];
    const float* Wo           = (const float*)d_in[9];
    float* out = (float*)d_out;

    char* ws = (char*)d_ws;
    int* maskN  = (int*)(ws + 0);          // 512 B
    int* meta   = (int*)(ws + 512);        // 64 B
    int* liveBt = (int*)(ws + 1024);       // 640 B (128+pad)
    int* grpSrc = (int*)(ws + 2048);       // 2720 B (640+pad)
    int* grpOut = (int*)(ws + 5120);       // 2720 B
    size_t off = 8192;
    unsigned short* WqT  = (unsigned short*)(ws + off); off += 1048576;   // 512*1024*2
    unsigned short* WkvT = (unsigned short*)(ws + off); off += 2097152;   // 1024*1024*2
    unsigned short* WoT  = (unsigned short*)(ws + off); off += 1048576;   // 1024*512*2
    unsigned short* kvin = (unsigned short*)(ws + off); off += 83886080;  // 128*320*1024*2
    unsigned short* qb   = (unsigned short*)(ws + off); off += 8388608;   // 128*64*512*2
    unsigned short* kb   = (unsigned short*)(ws + off); off += 41943040;  // 128*320*512*2
    unsigned short* vb   = (unsigned short*)(ws + off); off += 41943040;  // 128*512*320*2
    unsigned short* ab   = (unsigned short*)(ws + off); off += 8388608;   // 128*64*512*2

    hipLaunchKernelGGL(mask_kernel,  dim3(1),     dim3(64),  0, stream,
                       mraw, maskN, meta, liveBt, grpSrc, grpOut);
    hipLaunchKernelGGL(wprep_kernel, dim3(8192),  dim3(256), 0, stream,
                       Wq, Wkv, Wo, WqT, WkvT, WoT);
    hipLaunchKernelGGL(ln_kernel,    dim3(40960), dim3(256), 0, stream,
                       x, lat, gm, bm, gl, bl, maskN, kvin);
    hipLaunchKernelGGL((gemm128_kernel<0>), dim3(256),  dim3(256), 0, stream,
                       kvin, WqT,  meta, liveBt, grpSrc, grpOut, qb, kb, vb, out);
    hipLaunchKernelGGL((gemm128_kernel<1>), dim3(2560), dim3(256), 0, stream,
                       kvin, WkvT, meta, liveBt, grpSrc, grpOut, qb, kb, vb, out);
    hipLaunchKernelGGL(attn_kernel,         dim3(1024), dim3(256), 0, stream,
                       qb, kb, vb, meta, liveBt, ab);
    hipLaunchKernelGGL(zero_kernel,         dim3(128),  dim3(256), 0, stream,
                       maskN, out);
    hipLaunchKernelGGL((gemm128_kernel<2>), dim3(512),  dim3(256), 0, stream,
                       ab, WoT,  meta, liveBt, grpSrc, grpOut, qb, kb, vb, out);
}

// Round 9
// 192.764 us; speedup vs baseline: 1.2426x; 1.0131x over previous
//
#include <hip/hip_runtime.h>
#include <stdint.h>
#include <stddef.h>

#define B_      8
#define T_      16
#define NX_     256
#define NZ_     64
#define D_      1024
#define HEADS_  8
#define DHEAD_  64
#define INNER_  512
#define NKEY_   320          // NX_ + NZ_
#define NBT_    128          // B_*T_

typedef __attribute__((ext_vector_type(8))) short     short8;
typedef __attribute__((ext_vector_type(4))) float     f32x4;
typedef __attribute__((ext_vector_type(8))) unsigned short u16x8;

__device__ __forceinline__ unsigned short f2bf(float f) {
    union { float f; unsigned int u; } v; v.f = f;
    unsigned int u = v.u;
    return (unsigned short)((u + 0x7fffu + ((u >> 16) & 1u)) >> 16);
}

__device__ __forceinline__ void async16(unsigned short* lds, const unsigned short* g) {
    __builtin_amdgcn_global_load_lds(
        (const __attribute__((address_space(1))) void*)g,
        (__attribute__((address_space(3))) void*)lds, 16, 0, 0);
}

// bijective XCD-chunked swizzle over L live blocks (m204): blocks on the same
// XCD get a contiguous wg range -> neighbor tiles share L2-resident panels.
__device__ __forceinline__ int xcd_swz(int bid, int L) {
    int q = L >> 3, r = L & 7;
    int xcd = bid & 7, idx = bid >> 3;
    return (xcd < r ? xcd * (q + 1) : r * (q + 1) + (xcd - r) * q) + idx;
}

// ---------------------------------------------------------------------------
// mask normalization + live-compaction lists.
// ---------------------------------------------------------------------------
__global__ void mask_kernel(const unsigned char* __restrict__ mraw,
                            int* __restrict__ maskN, int* __restrict__ meta,
                            int* __restrict__ liveBt, int* __restrict__ grpSrc,
                            int* __restrict__ grpOut) {
    int lane = threadIdx.x;                 // 64 threads
    unsigned char b0 = mraw[lane];
    unsigned char b1 = mraw[lane + 64];
    bool nz = (((lane) & 3) != 0 && b0 != 0) || (((lane + 64) & 3) != 0 && b1 != 0);
    unsigned long long ball = __ballot(nz ? 1 : 0);
    bool isBool = (ball != 0ull);
    int v0, v1;
    if (isBool) { v0 = b0; v1 = b1; }
    else        { v0 = mraw[4 * lane]; v1 = mraw[4 * (lane + 64)]; }
    maskN[lane]      = v0 ? 1 : 0;
    maskN[lane + 64] = v1 ? 1 : 0;
    __syncthreads();
    if (lane == 0) {
        int nl = 0, ng = 0;
        for (int bt = 0; bt < NBT_; bt++) {
            if (maskN[bt]) {
                liveBt[nl++] = bt;
                #pragma unroll
                for (int g = 0; g < 5; g++) {
                    grpSrc[ng] = bt * NKEY_ + g * 64;
                    grpOut[ng] = (bt << 16) | (g * 64);
                    ng++;
                }
            }
        }
        if (nl & 1) liveBt[nl] = nl ? liveBt[nl - 1] : 0;
        if (ng & 1) { grpSrc[ng] = ng ? grpSrc[ng - 1] : 0;
                      grpOut[ng] = ng ? grpOut[ng - 1] : 0; }
        meta[0] = nl;
        meta[1] = (ng + 1) >> 1;
        meta[2] = (nl + 1) >> 1;
    }
}

// ---------------------------------------------------------------------------
// weight prep: f32 -> bf16, transposed to [N][K]
// ---------------------------------------------------------------------------
__global__ __launch_bounds__(256) void wprep_kernel(
        const float* __restrict__ Wq, const float* __restrict__ Wkv,
        const float* __restrict__ Wo,
        unsigned short* __restrict__ WqT, unsigned short* __restrict__ WkvT,
        unsigned short* __restrict__ WoT) {
    size_t id = (size_t)blockIdx.x * 256 + threadIdx.x;
    if (id < 524288) {                       // WqT[512][1024] <- Wq[1024][512]
        int n = (int)(id >> 10), k = (int)(id & 1023);
        WqT[id] = f2bf(Wq[(size_t)k * 512 + n]);
    } else if (id < 524288 + 1048576) {      // WkvT[1024][1024] <- Wkv[1024][1024]
        size_t j = id - 524288;
        int n = (int)(j >> 10), k = (int)(j & 1023);
        WkvT[j] = f2bf(Wkv[(size_t)k * 1024 + n]);
    } else {                                 // WoT[1024][512] <- Wo[512][1024]
        size_t j = id - 1572864;
        int n = (int)(j >> 9), k = (int)(j & 511);
        WoT[j] = f2bf(Wo[(size_t)k * 1024 + n]);
    }
}

// ---------------------------------------------------------------------------
// LayerNorm rows of x (32768) and latents (8192) -> bf16 packed kvin
// ---------------------------------------------------------------------------
__global__ __launch_bounds__(256) void ln_kernel(
        const float* __restrict__ x, const float* __restrict__ lat,
        const float* __restrict__ gm, const float* __restrict__ bm,
        const float* __restrict__ gl, const float* __restrict__ bl,
        const int* __restrict__ maskN,
        unsigned short* __restrict__ kvin) {
    int row = blockIdx.x;
    const float* src; unsigned short* dst; const float* g; const float* b;
    int bt;
    if (row < NBT_ * NX_) {
        bt = row >> 8;
        src = x + (size_t)row * D_;
        dst = kvin + ((size_t)bt * NKEY_ + (row & 255)) * D_;
        g = gm; b = bm;
    } else {
        int r = row - NBT_ * NX_;
        bt = r >> 6;
        src = lat + (size_t)r * D_;
        dst = kvin + ((size_t)bt * NKEY_ + 256 + (r & 63)) * D_;
        g = gl; b = bl;
    }
    if (!maskN[bt]) return;                  // masked (b,t): values never read
    int t = threadIdx.x;
    float4 v = reinterpret_cast<const float4*>(src)[t];
    float s  = v.x + v.y + v.z + v.w;
    float sq = v.x * v.x + v.y * v.y + v.z * v.z + v.w * v.w;
    #pragma unroll
    for (int off = 32; off > 0; off >>= 1) {
        s  += __shfl_down(s, off);
        sq += __shfl_down(sq, off);
    }
    __shared__ float red[8];
    int wid = t >> 6;
    if ((t & 63) == 0) { red[wid] = s; red[4 + wid] = sq; }
    __syncthreads();
    float stot = red[0] + red[1] + red[2] + red[3];
    float qtot = red[4] + red[5] + red[6] + red[7];
    float mean = stot * (1.0f / 1024.0f);
    float var  = qtot * (1.0f / 1024.0f) - mean * mean;
    float rstd = rsqrtf(var + 1e-5f);
    float4 gv = reinterpret_cast<const float4*>(g)[t];
    float4 bv = reinterpret_cast<const float4*>(b)[t];
    ushort4 o;
    o.x = f2bf((v.x - mean) * rstd * gv.x + bv.x);
    o.y = f2bf((v.y - mean) * rstd * gv.y + bv.y);
    o.z = f2bf((v.z - mean) * rstd * gv.z + bv.z);
    o.w = f2bf((v.w - mean) * rstd * gv.w + bv.w);
    *reinterpret_cast<ushort4*>(dst + 4 * t) = o;
}

// ---------------------------------------------------------------------------
// Compacted 2-phase dbuf GEMM (R5 schedule) + T1 bijective XCD swizzle.
// MODE 0: q  = zn(live) @ WqT,  *0.125, bf16
// MODE 1: kv = kvin(live grps) @ WkvT -> k[bt][320][512], vT[bt][512][320]
// MODE 2: out = ao(live) @ WoT, f32 (live rows only; dead rows zero_kernel)
// ---------------------------------------------------------------------------
template<int MODE>
__global__ __launch_bounds__(256) void gemm128_kernel(
        const unsigned short* __restrict__ A,
        const unsigned short* __restrict__ BT,
        const int* __restrict__ meta,
        const int* __restrict__ liveBt,
        const int* __restrict__ grpSrc,
        const int* __restrict__ grpOut,
        unsigned short* __restrict__ o_q,
        unsigned short* __restrict__ o_k,
        unsigned short* __restrict__ o_v,
        float* __restrict__ o_f) {
    constexpr int K     = (MODE == 2) ? 512 : 1024;
    constexpr int NSTEP = K / 64;
    constexpr int NTSH  = (MODE == 0) ? 2 : 3;                 // log2(N-tiles)

    int lim = (MODE == 1) ? meta[1] : meta[2];
    int L = lim << NTSH;                       // live block count
    int bid = blockIdx.x;
    if (bid >= L) return;
    int wg = xcd_swz(bid, L);                  // contiguous wg range per XCD;
    int mt = wg >> NTSH;                       // nt fastest -> A-panel reuse
    int nt = wg & ((1 << NTSH) - 1);           //   within one XCD's L2
    int n0 = nt * 128;
    int t = threadIdx.x;
    int lane = t & 63, wid = t >> 6;
    int lr = lane & 15, lg = lane >> 4;
    int wm = wid >> 1, wn = wid & 1;

    __shared__ __align__(16) unsigned short As[2][8192];   // 2 x 128x64
    __shared__ __align__(16) unsigned short Bs[2][8192];

    // per-lane global staging pointers through compaction maps
    const unsigned short* aptr[4];
    const unsigned short* bptr[4];
    #pragma unroll
    for (int i = 0; i < 4; i++) {
        int r128 = wid * 32 + i * 8 + (lane >> 3);         // 0..127, 8-row
        size_t srow;                                       // slices stay in-group
        if (MODE == 0) {
            int bt = liveBt[2 * mt + (r128 >> 6)];
            srow = (size_t)bt * NKEY_ + 256 + (r128 & 63);
        } else if (MODE == 1) {
            srow = (size_t)grpSrc[2 * mt + (r128 >> 6)] + (r128 & 63);
        } else {
            int bt = liveBt[2 * mt + (r128 >> 6)];
            srow = (size_t)bt * 64 + (r128 & 63);
        }
        aptr[i] = A + srow * K + (lane & 7) * 8;
        int brow = n0 + wid * 32 + i * 8 + (lane >> 3);
        bptr[i] = BT + (size_t)brow * K + (lane & 7) * 8;
    }

    f32x4 acc[4][4];
    #pragma unroll
    for (int i = 0; i < 4; i++)
        #pragma unroll
        for (int j = 0; j < 4; j++) acc[i][j] = (f32x4){0.f, 0.f, 0.f, 0.f};

    auto stage = [&](int buf) {
        unsigned short* as = &As[buf][wid * 2048];
        unsigned short* bs = &Bs[buf][wid * 2048];
        #pragma unroll
        for (int i = 0; i < 4; i++) {
            async16(as + i * 512, aptr[i]);
            async16(bs + i * 512, bptr[i]);
            aptr[i] += 64; bptr[i] += 64;
        }
    };
    auto compute = [&](int buf) {
        #pragma unroll
        for (int kc = 0; kc < 2; kc++) {
            short8 af[4], bf[4];
            #pragma unroll
            for (int mi = 0; mi < 4; mi++)
                af[mi] = *reinterpret_cast<const short8*>(
                    &As[buf][(wm * 64 + mi * 16 + lr) * 64 + kc * 32 + lg * 8]);
            #pragma unroll
            for (int ni = 0; ni < 4; ni++)
                bf[ni] = *reinterpret_cast<const short8*>(
                    &Bs[buf][(wn * 64 + ni * 16 + lr) * 64 + kc * 32 + lg * 8]);
            #pragma unroll
            for (int mi = 0; mi < 4; mi++)
                #pragma unroll
                for (int ni = 0; ni < 4; ni++)
                    acc[mi][ni] = __builtin_amdgcn_mfma_f32_16x16x32_bf16(
                        af[mi], bf[ni], acc[mi][ni], 0, 0, 0);
        }
    };

    #define FULL_STEP(CUR)                                              \
        stage((CUR) ^ 1);                                               \
        asm volatile("s_waitcnt vmcnt(8)" ::: "memory");                \
        __builtin_amdgcn_s_barrier();                                   \
        compute(CUR);                                                   \
        asm volatile("s_waitcnt lgkmcnt(0)" ::: "memory");              \
        __builtin_amdgcn_s_barrier();

    stage(0);
    #pragma unroll 1
    for (int ks2 = 0; ks2 < NSTEP / 2 - 1; ks2++) {
        FULL_STEP(0)
        FULL_STEP(1)
    }
    FULL_STEP(0)
    asm volatile("s_waitcnt vmcnt(0)" ::: "memory");
    __builtin_amdgcn_s_barrier();
    compute(1);
    #undef FULL_STEP

    #pragma unroll
    for (int mi = 0; mi < 4; mi++)
        #pragma unroll
        for (int ni = 0; ni < 4; ni++) {
            int rr = mi * 16 + lg * 4;                     // row in 64-group
            int c  = n0 + wn * 64 + ni * 16 + lr;
            if (MODE == 0) {
                int bt = liveBt[2 * mt + wm];
                #pragma unroll
                for (int r = 0; r < 4; r++)
                    o_q[((size_t)bt * 64 + rr + r) * 512 + c] =
                        f2bf(acc[mi][ni][r] * 0.125f);
            } else if (MODE == 1) {
                int enc = grpOut[2 * mt + wm];
                int bt = enc >> 16, krow = (enc & 0xffff) + rr;
                if (c < 512) {
                    #pragma unroll
                    for (int r = 0; r < 4; r++)
                        o_k[((size_t)bt * NKEY_ + krow + r) * 512 + c] =
                            f2bf(acc[mi][ni][r]);
                } else {
                    ushort4 pv;
                    pv.x = f2bf(acc[mi][ni][0]); pv.y = f2bf(acc[mi][ni][1]);
                    pv.z = f2bf(acc[mi][ni][2]); pv.w = f2bf(acc[mi][ni][3]);
                    *reinterpret_cast<ushort4*>(
                        o_v + ((size_t)bt * 512 + (c - 512)) * NKEY_ + krow) = pv;
                }
            } else {
                int bt = liveBt[2 * mt + wm];
                #pragma unroll
                for (int r = 0; r < 4; r++)
                    o_f[((size_t)bt * 64 + rr + r) * 1024 + c] = acc[mi][ni][r];
            }
        }
}

// ---------------------------------------------------------------------------
// zero-fill d_out rows of masked (b,t)
// ---------------------------------------------------------------------------
__global__ __launch_bounds__(256) void zero_kernel(const int* __restrict__ maskN,
                                                   float* __restrict__ out) {
    int bt = blockIdx.x;
    if (maskN[bt]) return;
    float4* p = reinterpret_cast<float4*>(out + (size_t)bt * 65536);
    float4 z = make_float4(0.f, 0.f, 0.f, 0.f);
    #pragma unroll
    for (int k = 0; k < 64; k++) p[k * 256 + threadIdx.x] = z;
}

// ---------------------------------------------------------------------------
// fused attention per live (bt,h): sim = q @ k^T (64x320), softmax, attn @ v
// XCD-swizzled so the 8 heads of one bt (sharing k/vT panels) co-locate.
// ---------------------------------------------------------------------------
__global__ __launch_bounds__(256) void attn_kernel(
        const unsigned short* __restrict__ q,
        const unsigned short* __restrict__ kbuf,
        const unsigned short* __restrict__ vbuf,   // vT [bt][512][320]
        const int* __restrict__ meta,
        const int* __restrict__ liveBt,
        unsigned short* __restrict__ ao) {
    int L = meta[0] << 3;
    int bid = blockIdx.x;
    if (bid >= L) return;
    int wg = xcd_swz(bid, L);
    int i = wg >> 3, h = wg & 7;
    int bt = liveBt[i];
    int t = threadIdx.x, w = t >> 6, lane = t & 63;
    int lr = lane & 15, lg = lane >> 4;
    __shared__ __align__(16) unsigned short attn_s[4][16][328];

    const unsigned short* qrow = q + ((size_t)bt * 64 + w * 16 + lr) * 512 + h * 64;
    short8 qa0 = *reinterpret_cast<const short8*>(qrow + lg * 8);
    short8 qa1 = *reinterpret_cast<const short8*>(qrow + 32 + lg * 8);

    f32x4 acc[20];
    #pragma unroll
    for (int i2 = 0; i2 < 20; i2++) acc[i2] = (f32x4){0.f, 0.f, 0.f, 0.f};

    const unsigned short* kb = kbuf + (size_t)bt * NKEY_ * 512 + h * 64;
    #pragma unroll
    for (int nt2 = 0; nt2 < 20; nt2++) {
        const unsigned short* krow = kb + (size_t)(nt2 * 16 + lr) * 512;
        short8 b0 = *reinterpret_cast<const short8*>(krow + lg * 8);
        short8 b1 = *reinterpret_cast<const short8*>(krow + 32 + lg * 8);
        acc[nt2] = __builtin_amdgcn_mfma_f32_16x16x32_bf16(qa0, b0, acc[nt2], 0, 0, 0);
        acc[nt2] = __builtin_amdgcn_mfma_f32_16x16x32_bf16(qa1, b1, acc[nt2], 0, 0, 0);
    }

    float mx[4], sm[4];
    #pragma unroll
    for (int r = 0; r < 4; r++) mx[r] = -1e30f;
    #pragma unroll
    for (int nt2 = 0; nt2 < 20; nt2++)
        #pragma unroll
        for (int r = 0; r < 4; r++) mx[r] = fmaxf(mx[r], acc[nt2][r]);
    #pragma unroll
    for (int r = 0; r < 4; r++) {
        #pragma unroll
        for (int off = 1; off < 16; off <<= 1)
            mx[r] = fmaxf(mx[r], __shfl_xor(mx[r], off));
        sm[r] = 0.f;
    }
    #pragma unroll
    for (int nt2 = 0; nt2 < 20; nt2++)
        #pragma unroll
        for (int r = 0; r < 4; r++) {
            float p = __expf(acc[nt2][r] - mx[r]);
            acc[nt2][r] = p;
            sm[r] += p;
        }
    #pragma unroll
    for (int r = 0; r < 4; r++) {
        #pragma unroll
        for (int off = 1; off < 16; off <<= 1)
            sm[r] += __shfl_xor(sm[r], off);
        sm[r] = 1.0f / sm[r];
    }
    #pragma unroll
    for (int nt2 = 0; nt2 < 20; nt2++)
        #pragma unroll
        for (int r = 0; r < 4; r++)
            attn_s[w][lg * 4 + r][nt2 * 16 + lr] = f2bf(acc[nt2][r] * sm[r]);
    __syncthreads();

    f32x4 o[4];
    #pragma unroll
    for (int i2 = 0; i2 < 4; i2++) o[i2] = (f32x4){0.f, 0.f, 0.f, 0.f};
    const unsigned short* vb = vbuf + (size_t)bt * 512 * NKEY_ + (size_t)h * 64 * NKEY_;
    #pragma unroll
    for (int kc = 0; kc < 10; kc++) {
        short8 pa = *reinterpret_cast<const short8*>(&attn_s[w][lr][kc * 32 + lg * 8]);
        #pragma unroll
        for (int ni = 0; ni < 4; ni++) {
            short8 vf = *reinterpret_cast<const short8*>(
                vb + (size_t)(ni * 16 + lr) * NKEY_ + kc * 32 + lg * 8);
            o[ni] = __builtin_amdgcn_mfma_f32_16x16x32_bf16(pa, vf, o[ni], 0, 0, 0);
        }
    }
    #pragma unroll
    for (int ni = 0; ni < 4; ni++)
        #pragma unroll
        for (int r = 0; r < 4; r++)
            ao[((size_t)bt * 64 + w * 16 + lg * 4 + r) * 512 + h * 64 + ni * 16 + lr] =
                f2bf(o[ni][r]);
}

// ---------------------------------------------------------------------------
extern "C" void kernel_launch(void* const* d_in, const int* in_sizes, int n_in,
                              void* d_out, int out_size, void* d_ws, size_t ws_size,
                              hipStream_t stream) {
    const float* x            = (const float*)d_in[0];
    const float* lat          = (const float*)d_in[1];
    const unsigned char* mraw = (const unsigned char*)d_in[2];
    const float* gm           = (const float*)d_in[3];
    const float* bm           = (const float*)d_in[4];
    const float* gl           = (const float*)d_in[5];
    const float* bl           = (const float*)d_in[6];
    const float* Wq           = (const float*)d_in[7];
    const float* Wkv          = (const float*)d_in[8];
    const float* Wo           = (const float*)d_in[9];
    float* out = (float*)d_out;

    char* ws = (char*)d_ws;
    int* maskN  = (int*)(ws + 0);          // 512 B
    int* meta   = (int*)(ws + 512);        // 64 B
    int* liveBt = (int*)(ws + 1024);       // 640 B (128+pad)
    int* grpSrc = (int*)(ws + 2048);       // 2720 B (640+pad)
    int* grpOut = (int*)(ws + 5120);       // 2720 B
    size_t off = 8192;
    unsigned short* WqT  = (unsigned short*)(ws + off); off += 1048576;   // 512*1024*2
    unsigned short* WkvT = (unsigned short*)(ws + off); off += 2097152;   // 1024*1024*2
    unsigned short* WoT  = (unsigned short*)(ws + off); off += 1048576;   // 1024*512*2
    unsigned short* kvin = (unsigned short*)(ws + off); off += 83886080;  // 128*320*1024*2
    unsigned short* qb   = (unsigned short*)(ws + off); off += 8388608;   // 128*64*512*2
    unsigned short* kb   = (unsigned short*)(ws + off); off += 41943040;  // 128*320*512*2
    unsigned short* vb   = (unsigned short*)(ws + off); off += 41943040;  // 128*512*320*2
    unsigned short* ab   = (unsigned short*)(ws + off); off += 8388608;   // 128*64*512*2

    hipLaunchKernelGGL(mask_kernel,  dim3(1),     dim3(64),  0, stream,
                       mraw, maskN, meta, liveBt, grpSrc, grpOut);
    hipLaunchKernelGGL(wprep_kernel, dim3(8192),  dim3(256), 0, stream,
                       Wq, Wkv, Wo, WqT, WkvT, WoT);
    hipLaunchKernelGGL(ln_kernel,    dim3(40960), dim3(256), 0, stream,
                       x, lat, gm, bm, gl, bl, maskN, kvin);
    hipLaunchKernelGGL((gemm128_kernel<0>), dim3(256),  dim3(256), 0, stream,
                       kvin, WqT,  meta, liveBt, grpSrc, grpOut, qb, kb, vb, out);
    hipLaunchKernelGGL((gemm128_kernel<1>), dim3(2560), dim3(256), 0, stream,
                       kvin, WkvT, meta, liveBt, grpSrc, grpOut, qb, kb, vb, out);
    hipLaunchKernelGGL(attn_kernel,         dim3(1024), dim3(256), 0, stream,
                       qb, kb, vb, meta, liveBt, ab);
    hipLaunchKernelGGL(zero_kernel,         dim3(128),  dim3(256), 0, stream,
                       maskN, out);
    hipLaunchKernelGGL((gemm128_kernel<2>), dim3(512),  dim3(256), 0, stream,
                       ab, WoT,  meta, liveBt, grpSrc, grpOut, qb, kb, vb, out);
}

// Round 10
// 189.355 us; speedup vs baseline: 1.2650x; 1.0180x over previous
//
#include <hip/hip_runtime.h>
#include <stdint.h>
#include <stddef.h>

#define B_      8
#define T_      16
#define NX_     256
#define NZ_     64
#define D_      1024
#define HEADS_  8
#define DHEAD_  64
#define INNER_  512
#define NKEY_   320          // NX_ + NZ_
#define NBT_    128          // B_*T_

typedef __attribute__((ext_vector_type(8))) short     short8;
typedef __attribute__((ext_vector_type(4))) float     f32x4;
typedef __attribute__((ext_vector_type(8))) unsigned short u16x8;

__device__ __forceinline__ unsigned short f2bf(float f) {
    union { float f; unsigned int u; } v; v.f = f;
    unsigned int u = v.u;
    return (unsigned short)((u + 0x7fffu + ((u >> 16) & 1u)) >> 16);
}

__device__ __forceinline__ void async16(unsigned short* lds, const unsigned short* g) {
    __builtin_amdgcn_global_load_lds(
        (const __attribute__((address_space(1))) void*)g,
        (__attribute__((address_space(3))) void*)lds, 16, 0, 0);
}

// bijective XCD-chunked swizzle over L live blocks (m204)
__device__ __forceinline__ int xcd_swz(int bid, int L) {
    int q = L >> 3, r = L & 7;
    int xcd = bid & 7, idx = bid >> 3;
    return (xcd < r ? xcd * (q + 1) : r * (q + 1) + (xcd - r) * q) + idx;
}

// ---------------------------------------------------------------------------
// mask normalization + live-compaction lists.
// meta[0]=nliveBt, meta[2]=bt-pair tiles (q/out), meta[3]=kv M-tiles (4 grps)
// ---------------------------------------------------------------------------
__global__ void mask_kernel(const unsigned char* __restrict__ mraw,
                            int* __restrict__ maskN, int* __restrict__ meta,
                            int* __restrict__ liveBt, int* __restrict__ grpSrc,
                            int* __restrict__ grpOut) {
    int lane = threadIdx.x;                 // 64 threads
    unsigned char b0 = mraw[lane];
    unsigned char b1 = mraw[lane + 64];
    bool nz = (((lane) & 3) != 0 && b0 != 0) || (((lane + 64) & 3) != 0 && b1 != 0);
    unsigned long long ball = __ballot(nz ? 1 : 0);
    bool isBool = (ball != 0ull);
    int v0, v1;
    if (isBool) { v0 = b0; v1 = b1; }
    else        { v0 = mraw[4 * lane]; v1 = mraw[4 * (lane + 64)]; }
    maskN[lane]      = v0 ? 1 : 0;
    maskN[lane + 64] = v1 ? 1 : 0;
    __syncthreads();
    if (lane == 0) {
        int nl = 0, ng = 0;
        for (int bt = 0; bt < NBT_; bt++) {
            if (maskN[bt]) {
                liveBt[nl++] = bt;
                #pragma unroll
                for (int g = 0; g < 5; g++) {
                    grpSrc[ng] = bt * NKEY_ + g * 64;
                    grpOut[ng] = (bt << 16) | (g * 64);
                    ng++;
                }
            }
        }
        if (nl & 1) liveBt[nl] = nl ? liveBt[nl - 1] : 0;
        while (ng & 3) {                        // pad to multiple of 4 groups
            grpSrc[ng] = ng ? grpSrc[ng - 1] : 0;
            grpOut[ng] = ng ? grpOut[ng - 1] : 0;
            ng++;
        }
        meta[0] = nl;
        meta[2] = (nl + 1) >> 1;
        meta[3] = ng >> 2;
    }
}

// ---------------------------------------------------------------------------
// weight prep: f32 -> bf16, transposed to [N][K]
// ---------------------------------------------------------------------------
__global__ __launch_bounds__(256) void wprep_kernel(
        const float* __restrict__ Wq, const float* __restrict__ Wkv,
        const float* __restrict__ Wo,
        unsigned short* __restrict__ WqT, unsigned short* __restrict__ WkvT,
        unsigned short* __restrict__ WoT) {
    size_t id = (size_t)blockIdx.x * 256 + threadIdx.x;
    if (id < 524288) {                       // WqT[512][1024] <- Wq[1024][512]
        int n = (int)(id >> 10), k = (int)(id & 1023);
        WqT[id] = f2bf(Wq[(size_t)k * 512 + n]);
    } else if (id < 524288 + 1048576) {      // WkvT[1024][1024] <- Wkv[1024][1024]
        size_t j = id - 524288;
        int n = (int)(j >> 10), k = (int)(j & 1023);
        WkvT[j] = f2bf(Wkv[(size_t)k * 1024 + n]);
    } else {                                 // WoT[1024][512] <- Wo[512][1024]
        size_t j = id - 1572864;
        int n = (int)(j >> 9), k = (int)(j & 511);
        WoT[j] = f2bf(Wo[(size_t)k * 1024 + n]);
    }
}

// ---------------------------------------------------------------------------
// LayerNorm rows of x (32768) and latents (8192) -> bf16 packed kvin
// ---------------------------------------------------------------------------
__global__ __launch_bounds__(256) void ln_kernel(
        const float* __restrict__ x, const float* __restrict__ lat,
        const float* __restrict__ gm, const float* __restrict__ bm,
        const float* __restrict__ gl, const float* __restrict__ bl,
        const int* __restrict__ maskN,
        unsigned short* __restrict__ kvin) {
    int row = blockIdx.x;
    const float* src; unsigned short* dst; const float* g; const float* b;
    int bt;
    if (row < NBT_ * NX_) {
        bt = row >> 8;
        src = x + (size_t)row * D_;
        dst = kvin + ((size_t)bt * NKEY_ + (row & 255)) * D_;
        g = gm; b = bm;
    } else {
        int r = row - NBT_ * NX_;
        bt = r >> 6;
        src = lat + (size_t)r * D_;
        dst = kvin + ((size_t)bt * NKEY_ + 256 + (r & 63)) * D_;
        g = gl; b = bl;
    }
    if (!maskN[bt]) return;                  // masked (b,t): values never read
    int t = threadIdx.x;
    float4 v = reinterpret_cast<const float4*>(src)[t];
    float s  = v.x + v.y + v.z + v.w;
    float sq = v.x * v.x + v.y * v.y + v.z * v.z + v.w * v.w;
    #pragma unroll
    for (int off = 32; off > 0; off >>= 1) {
        s  += __shfl_down(s, off);
        sq += __shfl_down(sq, off);
    }
    __shared__ float red[8];
    int wid = t >> 6;
    if ((t & 63) == 0) { red[wid] = s; red[4 + wid] = sq; }
    __syncthreads();
    float stot = red[0] + red[1] + red[2] + red[3];
    float qtot = red[4] + red[5] + red[6] + red[7];
    float mean = stot * (1.0f / 1024.0f);
    float var  = qtot * (1.0f / 1024.0f) - mean * mean;
    float rstd = rsqrtf(var + 1e-5f);
    float4 gv = reinterpret_cast<const float4*>(g)[t];
    float4 bv = reinterpret_cast<const float4*>(b)[t];
    ushort4 o;
    o.x = f2bf((v.x - mean) * rstd * gv.x + bv.x);
    o.y = f2bf((v.y - mean) * rstd * gv.y + bv.y);
    o.z = f2bf((v.z - mean) * rstd * gv.z + bv.z);
    o.w = f2bf((v.w - mean) * rstd * gv.w + bv.w);
    *reinterpret_cast<ushort4*>(dst + 4 * t) = o;
}

// ---------------------------------------------------------------------------
// kv-GEMM, 8-phase-class schedule: 256x256 tile, BK=32, 8 waves, THREE LDS
// buffers (96 KB) -> 2-K-tile prefetch distance -> TRUE counted vmcnt(4)
// (waits only tile t+1's 4 loads; t+2's stay in flight; never drains to 0
// in the main loop). T2 swizzle: slot ^= (row>>1)&3 (involution, bits 4-5
// keyed by untouched bits 7-8; 16-way -> 2-way on stride-64B ds_read_b128),
// applied as pre-swizzled global source + swizzled read (rule 21).
// T5 setprio around each 16-MFMA cluster (phase-split prerequisite present).
// ---------------------------------------------------------------------------
__global__ __launch_bounds__(512) void gemm256_kv(
        const unsigned short* __restrict__ A,
        const unsigned short* __restrict__ BT,
        const int* __restrict__ meta,
        const int* __restrict__ grpSrc,
        const int* __restrict__ grpOut,
        unsigned short* __restrict__ o_k,
        unsigned short* __restrict__ o_v) {
    int L = meta[3] << 2;                      // live blocks (mt x 4 nt)
    if (blockIdx.x >= L) return;
    int wg = xcd_swz(blockIdx.x, L);
    int mt = wg >> 2, nt = wg & 3;
    int n0 = nt * 256;
    int t = threadIdx.x, lane = t & 63, w = t >> 6;
    int lr = lane & 15, lg = lane >> 4;
    int wm = w >> 2, wn = w & 3;               // wave grid 2M x 4N

    __shared__ __align__(16) unsigned short As[3][8192];   // 3 x 256x32
    __shared__ __align__(16) unsigned short Bs[3][8192];

    // --- staging: per K-tile, A = 2 issues (128 rows x 64B each), B = 2.
    // LDS linear; global source col pre-swizzled (rule 21).
    int swzslot = (t & 3) ^ ((t >> 3) & 3);    // source 16B-slot for this lane
    const unsigned short* aSrc[2];
    const unsigned short* bSrc[2];
    #pragma unroll
    for (int j = 0; j < 2; j++) {
        int srcRow = grpSrc[4 * mt + j * 2 + (t >> 8)] + ((t >> 2) & 63);
        aSrc[j] = A  + (size_t)srcRow * 1024 + swzslot * 8;
        bSrc[j] = BT + (size_t)(n0 + j * 128 + (t >> 2)) * 1024 + swzslot * 8;
    }
    #define STAGE_A(SB, K0) {                                          \
        async16(&As[SB][w * 512],        aSrc[0] + (K0));              \
        async16(&As[SB][4096 + w * 512], aSrc[1] + (K0)); }
    #define STAGE_B(SB, K0) {                                          \
        async16(&Bs[SB][w * 512],        bSrc[0] + (K0));              \
        async16(&Bs[SB][4096 + w * 512], bSrc[1] + (K0)); }

    // --- swizzled fragment reads: row*32 elems + (lg ^ ((lr>>1)&3))*8
    int acol = (lg ^ ((lr >> 1) & 3)) * 8;
    #define LDA(BUF, MH, MI) (*reinterpret_cast<const short8*>(        \
        &As[BUF][(wm * 128 + (MH) * 64 + (MI) * 16 + lr) * 32 + acol]))
    #define LDB(BUF, NI) (*reinterpret_cast<const short8*>(            \
        &Bs[BUF][(wn * 64 + (NI) * 16 + lr) * 32 + acol]))

    f32x4 acc[8][4];
    #pragma unroll
    for (int i = 0; i < 8; i++)
        #pragma unroll
        for (int j = 0; j < 4; j++) acc[i][j] = (f32x4){0.f, 0.f, 0.f, 0.f};
    short8 bfr[4];

    #define MFMA16(MH, A0, A1, A2, A3) {                               \
        _Pragma("unroll")                                              \
        for (int ni = 0; ni < 4; ni++) {                               \
            acc[(MH)*4+0][ni] = __builtin_amdgcn_mfma_f32_16x16x32_bf16(A0, bfr[ni], acc[(MH)*4+0][ni], 0, 0, 0); \
            acc[(MH)*4+1][ni] = __builtin_amdgcn_mfma_f32_16x16x32_bf16(A1, bfr[ni], acc[(MH)*4+1][ni], 0, 0, 0); \
            acc[(MH)*4+2][ni] = __builtin_amdgcn_mfma_f32_16x16x32_bf16(A2, bfr[ni], acc[(MH)*4+2][ni], 0, 0, 0); \
            acc[(MH)*4+3][ni] = __builtin_amdgcn_mfma_f32_16x16x32_bf16(A3, bfr[ni], acc[(MH)*4+3][ni], 0, 0, 0); } }

    // phase 1: stage A-half of tile t+2; read 8 frags; 16 MFMA (mh=0)
    #define PHASE1(BUF, SB, K0, DOST) {                                \
        if (DOST) STAGE_A(SB, K0);                                     \
        short8 a0 = LDA(BUF, 0, 0), a1 = LDA(BUF, 0, 1),               \
               a2 = LDA(BUF, 0, 2), a3 = LDA(BUF, 0, 3);               \
        bfr[0] = LDB(BUF, 0); bfr[1] = LDB(BUF, 1);                    \
        bfr[2] = LDB(BUF, 2); bfr[3] = LDB(BUF, 3);                    \
        __builtin_amdgcn_s_barrier();                                  \
        __builtin_amdgcn_s_setprio(1);                                 \
        MFMA16(0, a0, a1, a2, a3)                                      \
        __builtin_amdgcn_s_setprio(0);                                 \
        __builtin_amdgcn_s_barrier(); }

    // phase 2: stage B-half of t+2; read 4 frags; counted wait; 16 MFMA (mh=1)
    #define PHASE2(BUF, SB, K0, DOST, VMST) {                          \
        if (DOST) STAGE_B(SB, K0);                                     \
        short8 a0 = LDA(BUF, 1, 0), a1 = LDA(BUF, 1, 1),               \
               a2 = LDA(BUF, 1, 2), a3 = LDA(BUF, 1, 3);               \
        VMST;                                                          \
        __builtin_amdgcn_s_barrier();                                  \
        __builtin_amdgcn_s_setprio(1);                                 \
        MFMA16(1, a0, a1, a2, a3)                                      \
        __builtin_amdgcn_s_setprio(0);                                 \
        __builtin_amdgcn_s_barrier(); }

    #define VM4 asm volatile("s_waitcnt vmcnt(4)" ::: "memory")
    #define VM0 asm volatile("s_waitcnt vmcnt(0)" ::: "memory")

    // prologue: stage tiles 0,1; wait tile 0 only (tile 1 stays in flight)
    STAGE_A(0, 0)  STAGE_B(0, 0)
    STAGE_A(1, 32) STAGE_B(1, 32)
    VM4;
    __builtin_amdgcn_s_barrier();

    // 32 K-tiles: t=0..29 in loop (buf = t%3, stage t+2 -> buf[(t+2)%3])
    #pragma unroll 1
    for (int i = 0; i < 10; i++) {
        int k0 = i * 96;
        PHASE1(0, 2, k0 + 64,  true)
        PHASE2(0, 2, k0 + 64,  true, VM4)
        PHASE1(1, 0, k0 + 96,  true)
        PHASE2(1, 0, k0 + 96,  true, VM4)
        PHASE1(2, 1, k0 + 128, true)
        PHASE2(2, 1, k0 + 128, true, VM4)
    }
    PHASE1(0, 0, 0, false)                     // tile 30 (buf 0)
    PHASE2(0, 0, 0, false, VM0)                //   drain tile 31's loads
    PHASE1(1, 0, 0, false)                     // tile 31 (buf 1)
    PHASE2(1, 0, 0, false, ((void)0))
    #undef PHASE1
    #undef PHASE2
    #undef MFMA16
    #undef LDA
    #undef LDB
    #undef STAGE_A
    #undef STAGE_B

    // epilogue: rows wm*128 + (mi2>>2)*64 + (mi2&3)*16 + lg*4 + r
    int enc0 = grpOut[4 * mt + wm * 2];
    int enc1 = grpOut[4 * mt + wm * 2 + 1];
    #pragma unroll
    for (int mi2 = 0; mi2 < 8; mi2++) {
        int enc = (mi2 < 4) ? enc0 : enc1;
        int bt = enc >> 16;
        int krow = (enc & 0xffff) + (mi2 & 3) * 16 + lg * 4;
        #pragma unroll
        for (int ni = 0; ni < 4; ni++) {
            int c = n0 + wn * 64 + ni * 16 + lr;
            if (c < 512) {
                #pragma unroll
                for (int r = 0; r < 4; r++)
                    o_k[((size_t)bt * NKEY_ + krow + r) * 512 + c] =
                        f2bf(acc[mi2][ni][r]);
            } else {
                ushort4 pv;
                pv.x = f2bf(acc[mi2][ni][0]); pv.y = f2bf(acc[mi2][ni][1]);
                pv.z = f2bf(acc[mi2][ni][2]); pv.w = f2bf(acc[mi2][ni][3]);
                *reinterpret_cast<ushort4*>(
                    o_v + ((size_t)bt * 512 + (c - 512)) * NKEY_ + krow) = pv;
            }
        }
    }
}

// ---------------------------------------------------------------------------
// Compacted 2-phase dbuf GEMM (R5 schedule) + T1 swizzle (q and out only).
// MODE 0: q  = zn(live) @ WqT,  *0.125, bf16
// MODE 2: out = ao(live) @ WoT, f32 (live rows only; dead rows zero_kernel)
// ---------------------------------------------------------------------------
template<int MODE>
__global__ __launch_bounds__(256) void gemm128_kernel(
        const unsigned short* __restrict__ A,
        const unsigned short* __restrict__ BT,
        const int* __restrict__ meta,
        const int* __restrict__ liveBt,
        unsigned short* __restrict__ o_q,
        float* __restrict__ o_f) {
    constexpr int K     = (MODE == 2) ? 512 : 1024;
    constexpr int NSTEP = K / 64;
    constexpr int NTSH  = (MODE == 0) ? 2 : 3;                 // log2(N-tiles)

    int lim = meta[2];
    int L = lim << NTSH;
    int bid = blockIdx.x;
    if (bid >= L) return;
    int wg = xcd_swz(bid, L);
    int mt = wg >> NTSH;
    int nt = wg & ((1 << NTSH) - 1);
    int n0 = nt * 128;
    int t = threadIdx.x;
    int lane = t & 63, wid = t >> 6;
    int lr = lane & 15, lg = lane >> 4;
    int wm = wid >> 1, wn = wid & 1;

    __shared__ __align__(16) unsigned short As[2][8192];   // 2 x 128x64
    __shared__ __align__(16) unsigned short Bs[2][8192];

    const unsigned short* aptr[4];
    const unsigned short* bptr[4];
    #pragma unroll
    for (int i = 0; i < 4; i++) {
        int r128 = wid * 32 + i * 8 + (lane >> 3);
        int bt = liveBt[2 * mt + (r128 >> 6)];
        size_t srow;
        if (MODE == 0) srow = (size_t)bt * NKEY_ + 256 + (r128 & 63);
        else           srow = (size_t)bt * 64 + (r128 & 63);
        aptr[i] = A + srow * K + (lane & 7) * 8;
        int brow = n0 + wid * 32 + i * 8 + (lane >> 3);
        bptr[i] = BT + (size_t)brow * K + (lane & 7) * 8;
    }

    f32x4 acc[4][4];
    #pragma unroll
    for (int i = 0; i < 4; i++)
        #pragma unroll
        for (int j = 0; j < 4; j++) acc[i][j] = (f32x4){0.f, 0.f, 0.f, 0.f};

    auto stage = [&](int buf) {
        unsigned short* as = &As[buf][wid * 2048];
        unsigned short* bs = &Bs[buf][wid * 2048];
        #pragma unroll
        for (int i = 0; i < 4; i++) {
            async16(as + i * 512, aptr[i]);
            async16(bs + i * 512, bptr[i]);
            aptr[i] += 64; bptr[i] += 64;
        }
    };
    auto compute = [&](int buf) {
        #pragma unroll
        for (int kc = 0; kc < 2; kc++) {
            short8 af[4], bf[4];
            #pragma unroll
            for (int mi = 0; mi < 4; mi++)
                af[mi] = *reinterpret_cast<const short8*>(
                    &As[buf][(wm * 64 + mi * 16 + lr) * 64 + kc * 32 + lg * 8]);
            #pragma unroll
            for (int ni = 0; ni < 4; ni++)
                bf[ni] = *reinterpret_cast<const short8*>(
                    &Bs[buf][(wn * 64 + ni * 16 + lr) * 64 + kc * 32 + lg * 8]);
            #pragma unroll
            for (int mi = 0; mi < 4; mi++)
                #pragma unroll
                for (int ni = 0; ni < 4; ni++)
                    acc[mi][ni] = __builtin_amdgcn_mfma_f32_16x16x32_bf16(
                        af[mi], bf[ni], acc[mi][ni], 0, 0, 0);
        }
    };

    #define FULL_STEP(CUR)                                              \
        stage((CUR) ^ 1);                                               \
        asm volatile("s_waitcnt vmcnt(8)" ::: "memory");                \
        __builtin_amdgcn_s_barrier();                                   \
        compute(CUR);                                                   \
        asm volatile("s_waitcnt lgkmcnt(0)" ::: "memory");              \
        __builtin_amdgcn_s_barrier();

    stage(0);
    #pragma unroll 1
    for (int ks2 = 0; ks2 < NSTEP / 2 - 1; ks2++) {
        FULL_STEP(0)
        FULL_STEP(1)
    }
    FULL_STEP(0)
    asm volatile("s_waitcnt vmcnt(0)" ::: "memory");
    __builtin_amdgcn_s_barrier();
    compute(1);
    #undef FULL_STEP

    #pragma unroll
    for (int mi = 0; mi < 4; mi++)
        #pragma unroll
        for (int ni = 0; ni < 4; ni++) {
            int rr = mi * 16 + lg * 4;
            int c  = n0 + wn * 64 + ni * 16 + lr;
            int bt = liveBt[2 * mt + wm];
            if (MODE == 0) {
                #pragma unroll
                for (int r = 0; r < 4; r++)
                    o_q[((size_t)bt * 64 + rr + r) * 512 + c] =
                        f2bf(acc[mi][ni][r] * 0.125f);
            } else {
                #pragma unroll
                for (int r = 0; r < 4; r++)
                    o_f[((size_t)bt * 64 + rr + r) * 1024 + c] = acc[mi][ni][r];
            }
        }
}

// ---------------------------------------------------------------------------
// zero-fill d_out rows of masked (b,t)
// ---------------------------------------------------------------------------
__global__ __launch_bounds__(256) void zero_kernel(const int* __restrict__ maskN,
                                                   float* __restrict__ out) {
    int bt = blockIdx.x;
    if (maskN[bt]) return;
    float4* p = reinterpret_cast<float4*>(out + (size_t)bt * 65536);
    float4 z = make_float4(0.f, 0.f, 0.f, 0.f);
    #pragma unroll
    for (int k = 0; k < 64; k++) p[k * 256 + threadIdx.x] = z;
}

// ---------------------------------------------------------------------------
// fused attention per live (bt,h): sim = q @ k^T (64x320), softmax, attn @ v
// ---------------------------------------------------------------------------
__global__ __launch_bounds__(256) void attn_kernel(
        const unsigned short* __restrict__ q,
        const unsigned short* __restrict__ kbuf,
        const unsigned short* __restrict__ vbuf,   // vT [bt][512][320]
        const int* __restrict__ meta,
        const int* __restrict__ liveBt,
        unsigned short* __restrict__ ao) {
    int L = meta[0] << 3;
    int bid = blockIdx.x;
    if (bid >= L) return;
    int wg = xcd_swz(bid, L);
    int i = wg >> 3, h = wg & 7;
    int bt = liveBt[i];
    int t = threadIdx.x, w = t >> 6, lane = t & 63;
    int lr = lane & 15, lg = lane >> 4;
    __shared__ __align__(16) unsigned short attn_s[4][16][328];

    const unsigned short* qrow = q + ((size_t)bt * 64 + w * 16 + lr) * 512 + h * 64;
    short8 qa0 = *reinterpret_cast<const short8*>(qrow + lg * 8);
    short8 qa1 = *reinterpret_cast<const short8*>(qrow + 32 + lg * 8);

    f32x4 acc[20];
    #pragma unroll
    for (int i2 = 0; i2 < 20; i2++) acc[i2] = (f32x4){0.f, 0.f, 0.f, 0.f};

    const unsigned short* kb = kbuf + (size_t)bt * NKEY_ * 512 + h * 64;
    #pragma unroll
    for (int nt2 = 0; nt2 < 20; nt2++) {
        const unsigned short* krow = kb + (size_t)(nt2 * 16 + lr) * 512;
        short8 b0 = *reinterpret_cast<const short8*>(krow + lg * 8);
        short8 b1 = *reinterpret_cast<const short8*>(krow + 32 + lg * 8);
        acc[nt2] = __builtin_amdgcn_mfma_f32_16x16x32_bf16(qa0, b0, acc[nt2], 0, 0, 0);
        acc[nt2] = __builtin_amdgcn_mfma_f32_16x16x32_bf16(qa1, b1, acc[nt2], 0, 0, 0);
    }

    float mx[4], sm[4];
    #pragma unroll
    for (int r = 0; r < 4; r++) mx[r] = -1e30f;
    #pragma unroll
    for (int nt2 = 0; nt2 < 20; nt2++)
        #pragma unroll
        for (int r = 0; r < 4; r++) mx[r] = fmaxf(mx[r], acc[nt2][r]);
    #pragma unroll
    for (int r = 0; r < 4; r++) {
        #pragma unroll
        for (int off = 1; off < 16; off <<= 1)
            mx[r] = fmaxf(mx[r], __shfl_xor(mx[r], off));
        sm[r] = 0.f;
    }
    #pragma unroll
    for (int nt2 = 0; nt2 < 20; nt2++)
        #pragma unroll
        for (int r = 0; r < 4; r++) {
            float p = __expf(acc[nt2][r] - mx[r]);
            acc[nt2][r] = p;
            sm[r] += p;
        }
    #pragma unroll
    for (int r = 0; r < 4; r++) {
        #pragma unroll
        for (int off = 1; off < 16; off <<= 1)
            sm[r] += __shfl_xor(sm[r], off);
        sm[r] = 1.0f / sm[r];
    }
    #pragma unroll
    for (int nt2 = 0; nt2 < 20; nt2++)
        #pragma unroll
        for (int r = 0; r < 4; r++)
            attn_s[w][lg * 4 + r][nt2 * 16 + lr] = f2bf(acc[nt2][r] * sm[r]);
    __syncthreads();

    f32x4 o[4];
    #pragma unroll
    for (int i2 = 0; i2 < 4; i2++) o[i2] = (f32x4){0.f, 0.f, 0.f, 0.f};
    const unsigned short* vb = vbuf + (size_t)bt * 512 * NKEY_ + (size_t)h * 64 * NKEY_;
    #pragma unroll
    for (int kc = 0; kc < 10; kc++) {
        short8 pa = *reinterpret_cast<const short8*>(&attn_s[w][lr][kc * 32 + lg * 8]);
        #pragma unroll
        for (int ni = 0; ni < 4; ni++) {
            short8 vf = *reinterpret_cast<const short8*>(
                vb + (size_t)(ni * 16 + lr) * NKEY_ + kc * 32 + lg * 8);
            o[ni] = __builtin_amdgcn_mfma_f32_16x16x32_bf16(pa, vf, o[ni], 0, 0, 0);
        }
    }
    #pragma unroll
    for (int ni = 0; ni < 4; ni++)
        #pragma unroll
        for (int r = 0; r < 4; r++)
            ao[((size_t)bt * 64 + w * 16 + lg * 4 + r) * 512 + h * 64 + ni * 16 + lr] =
                f2bf(o[ni][r]);
}

// ---------------------------------------------------------------------------
extern "C" void kernel_launch(void* const* d_in, const int* in_sizes, int n_in,
                              void* d_out, int out_size, void* d_ws, size_t ws_size,
                              hipStream_t stream) {
    const float* x            = (const float*)d_in[0];
    const float* lat          = (const float*)d_in[1];
    const unsigned char* mraw = (const unsigned char*)d_in[2];
    const float* gm           = (const float*)d_in[3];
    const float* bm           = (const float*)d_in[4];
    const float* gl           = (const float*)d_in[5];
    const float* bl           = (const float*)d_in[6];
    const float* Wq           = (const float*)d_in[7];
    const float* Wkv          = (const float*)d_in[8];
    const float* Wo           = (const float*)d_in[9];
    float* out = (float*)d_out;

    char* ws = (char*)d_ws;
    int* maskN  = (int*)(ws + 0);          // 512 B
    int* meta   = (int*)(ws + 512);        // 64 B
    int* liveBt = (int*)(ws + 1024);       // 640 B
    int* grpSrc = (int*)(ws + 2048);       // ~2.6 KB
    int* grpOut = (int*)(ws + 5120);       // ~2.6 KB
    size_t off = 8192;
    unsigned short* WqT  = (unsigned short*)(ws + off); off += 1048576;   // 512*1024*2
    unsigned short* WkvT = (unsigned short*)(ws + off); off += 2097152;   // 1024*1024*2
    unsigned short* WoT  = (unsigned short*)(ws + off); off += 1048576;   // 1024*512*2
    unsigned short* kvin = (unsigned short*)(ws + off); off += 83886080;  // 128*320*1024*2
    unsigned short* qb   = (unsigned short*)(ws + off); off += 8388608;   // 128*64*512*2
    unsigned short* kb   = (unsigned short*)(ws + off); off += 41943040;  // 128*320*512*2
    unsigned short* vb   = (unsigned short*)(ws + off); off += 41943040;  // 128*512*320*2
    unsigned short* ab   = (unsigned short*)(ws + off); off += 8388608;   // 128*64*512*2

    hipLaunchKernelGGL(mask_kernel,  dim3(1),     dim3(64),  0, stream,
                       mraw, maskN, meta, liveBt, grpSrc, grpOut);
    hipLaunchKernelGGL(wprep_kernel, dim3(8192),  dim3(256), 0, stream,
                       Wq, Wkv, Wo, WqT, WkvT, WoT);
    hipLaunchKernelGGL(ln_kernel,    dim3(40960), dim3(256), 0, stream,
                       x, lat, gm, bm, gl, bl, maskN, kvin);
    hipLaunchKernelGGL((gemm128_kernel<0>), dim3(256),  dim3(256), 0, stream,
                       kvin, WqT,  meta, liveBt, qb, out);
    hipLaunchKernelGGL(gemm256_kv,          dim3(640),  dim3(512), 0, stream,
                       kvin, WkvT, meta, grpSrc, grpOut, kb, vb);
    hipLaunchKernelGGL(attn_kernel,         dim3(1024), dim3(256), 0, stream,
                       qb, kb, vb, meta, liveBt, ab);
    hipLaunchKernelGGL(zero_kernel,         dim3(128),  dim3(256), 0, stream,
                       maskN, out);
    hipLaunchKernelGGL((gemm128_kernel<2>), dim3(512),  dim3(256), 0, stream,
                       ab, WoT,  meta, liveBt, qb, out);
}

// Round 12
// 177.402 us; speedup vs baseline: 1.3502x; 1.0674x over previous
//
#include <hip/hip_runtime.h>
#include <stdint.h>
#include <stddef.h>

#define B_      8
#define T_      16
#define NX_     256
#define NZ_     64
#define D_      1024
#define HEADS_  8
#define DHEAD_  64
#define INNER_  512
#define NKEY_   320          // NX_ + NZ_
#define NBT_    128          // B_*T_

typedef __attribute__((ext_vector_type(8))) short     short8;
typedef __attribute__((ext_vector_type(4))) float     f32x4;
typedef __attribute__((ext_vector_type(8))) unsigned short u16x8;

__device__ __forceinline__ unsigned short f2bf(float f) {
    union { float f; unsigned int u; } v; v.f = f;
    unsigned int u = v.u;
    return (unsigned short)((u + 0x7fffu + ((u >> 16) & 1u)) >> 16);
}

__device__ __forceinline__ void async16(unsigned short* lds, const unsigned short* g) {
    __builtin_amdgcn_global_load_lds(
        (const __attribute__((address_space(1))) void*)g,
        (__attribute__((address_space(3))) void*)lds, 16, 0, 0);
}

// bijective XCD-chunked swizzle over L live blocks (m204)
__device__ __forceinline__ int xcd_swz(int bid, int L) {
    int q = L >> 3, r = L & 7;
    int xcd = bid & 7, idx = bid >> 3;
    return (xcd < r ? xcd * (q + 1) : r * (q + 1) + (xcd - r) * q) + idx;
}

// ---------------------------------------------------------------------------
// mask normalization + live-compaction lists.
// meta[0]=nliveBt, meta[1]=#kv M-tiles (live-64-row-group pairs),
// meta[2]=#bt-pair tiles for q/out GEMMs.
// ---------------------------------------------------------------------------
__global__ void mask_kernel(const unsigned char* __restrict__ mraw,
                            int* __restrict__ maskN, int* __restrict__ meta,
                            int* __restrict__ liveBt, int* __restrict__ grpSrc,
                            int* __restrict__ grpOut) {
    int lane = threadIdx.x;                 // 64 threads
    unsigned char b0 = mraw[lane];
    unsigned char b1 = mraw[lane + 64];
    bool nz = (((lane) & 3) != 0 && b0 != 0) || (((lane + 64) & 3) != 0 && b1 != 0);
    unsigned long long ball = __ballot(nz ? 1 : 0);
    bool isBool = (ball != 0ull);
    int v0, v1;
    if (isBool) { v0 = b0; v1 = b1; }
    else        { v0 = mraw[4 * lane]; v1 = mraw[4 * (lane + 64)]; }
    maskN[lane]      = v0 ? 1 : 0;
    maskN[lane + 64] = v1 ? 1 : 0;
    __syncthreads();
    if (lane == 0) {
        int nl = 0, ng = 0;
        for (int bt = 0; bt < NBT_; bt++) {
            if (maskN[bt]) {
                liveBt[nl++] = bt;
                #pragma unroll
                for (int g = 0; g < 5; g++) {
                    grpSrc[ng] = bt * NKEY_ + g * 64;
                    grpOut[ng] = (bt << 16) | (g * 64);
                    ng++;
                }
            }
        }
        if (nl & 1) liveBt[nl] = nl ? liveBt[nl - 1] : 0;
        if (ng & 1) { grpSrc[ng] = ng ? grpSrc[ng - 1] : 0;
                      grpOut[ng] = ng ? grpOut[ng - 1] : 0; }
        meta[0] = nl;
        meta[1] = (ng + 1) >> 1;
        meta[2] = (nl + 1) >> 1;
    }
}

// ---------------------------------------------------------------------------
// weight prep: f32 -> bf16, transposed to [N][K]
// ---------------------------------------------------------------------------
__global__ __launch_bounds__(256) void wprep_kernel(
        const float* __restrict__ Wq, const float* __restrict__ Wkv,
        const float* __restrict__ Wo,
        unsigned short* __restrict__ WqT, unsigned short* __restrict__ WkvT,
        unsigned short* __restrict__ WoT) {
    size_t id = (size_t)blockIdx.x * 256 + threadIdx.x;
    if (id < 524288) {                       // WqT[512][1024] <- Wq[1024][512]
        int n = (int)(id >> 10), k = (int)(id & 1023);
        WqT[id] = f2bf(Wq[(size_t)k * 512 + n]);
    } else if (id < 524288 + 1048576) {      // WkvT[1024][1024] <- Wkv[1024][1024]
        size_t j = id - 524288;
        int n = (int)(j >> 10), k = (int)(j & 1023);
        WkvT[j] = f2bf(Wkv[(size_t)k * 1024 + n]);
    } else {                                 // WoT[1024][512] <- Wo[512][1024]
        size_t j = id - 1572864;
        int n = (int)(j >> 9), k = (int)(j & 511);
        WoT[j] = f2bf(Wo[(size_t)k * 1024 + n]);
    }
}

// ---------------------------------------------------------------------------
// LayerNorm rows of x (32768) and latents (8192) -> bf16 packed kvin
// ---------------------------------------------------------------------------
__global__ __launch_bounds__(256) void ln_kernel(
        const float* __restrict__ x, const float* __restrict__ lat,
        const float* __restrict__ gm, const float* __restrict__ bm,
        const float* __restrict__ gl, const float* __restrict__ bl,
        const int* __restrict__ maskN,
        unsigned short* __restrict__ kvin) {
    int row = blockIdx.x;
    const float* src; unsigned short* dst; const float* g; const float* b;
    int bt;
    if (row < NBT_ * NX_) {
        bt = row >> 8;
        src = x + (size_t)row * D_;
        dst = kvin + ((size_t)bt * NKEY_ + (row & 255)) * D_;
        g = gm; b = bm;
    } else {
        int r = row - NBT_ * NX_;
        bt = r >> 6;
        src = lat + (size_t)r * D_;
        dst = kvin + ((size_t)bt * NKEY_ + 256 + (r & 63)) * D_;
        g = gl; b = bl;
    }
    if (!maskN[bt]) return;                  // masked (b,t): values never read
    int t = threadIdx.x;
    float4 v = reinterpret_cast<const float4*>(src)[t];
    float s  = v.x + v.y + v.z + v.w;
    float sq = v.x * v.x + v.y * v.y + v.z * v.z + v.w * v.w;
    #pragma unroll
    for (int off = 32; off > 0; off >>= 1) {
        s  += __shfl_down(s, off);
        sq += __shfl_down(sq, off);
    }
    __shared__ float red[8];
    int wid = t >> 6;
    if ((t & 63) == 0) { red[wid] = s; red[4 + wid] = sq; }
    __syncthreads();
    float stot = red[0] + red[1] + red[2] + red[3];
    float qtot = red[4] + red[5] + red[6] + red[7];
    float mean = stot * (1.0f / 1024.0f);
    float var  = qtot * (1.0f / 1024.0f) - mean * mean;
    float rstd = rsqrtf(var + 1e-5f);
    float4 gv = reinterpret_cast<const float4*>(g)[t];
    float4 bv = reinterpret_cast<const float4*>(b)[t];
    ushort4 o;
    o.x = f2bf((v.x - mean) * rstd * gv.x + bv.x);
    o.y = f2bf((v.y - mean) * rstd * gv.y + bv.y);
    o.z = f2bf((v.z - mean) * rstd * gv.z + bv.z);
    o.w = f2bf((v.w - mean) * rstd * gv.w + bv.w);
    *reinterpret_cast<ushort4*>(dst + 4 * t) = o;
}

// ---------------------------------------------------------------------------
// Compacted dbuf GEMM, BK=32 high-residency variant: 128x128 tile, 4 waves,
// 32 KB LDS -> 4 blocks/CU (launch_bounds(256,4)), counted vmcnt(4).
// LDS mapping derived per-lane from the wave-uniform gload_lds rule:
//   issue (wid,j) -> LDS base (wid*2+j)*512 shorts; lane l writes
//   row R=(wid*2+j)*16+(l>>2), slot l&3 -> global source (R, slot).
// BK=32 row-major (64B rows) is at the b128 bank-conflict floor (each row's
// 4 lanes cover all four 16B slots; even/odd rows split bank halves) -> no
// swizzle needed.
// MODE 0: q  = zn(live) @ WqT,  *0.125, bf16
// MODE 1: kv = kvin(live grps) @ WkvT -> k[bt][320][512], vT[bt][512][320]
// MODE 2: out = ao(live) @ WoT, f32 (live rows; dead rows via zero_kernel)
// ---------------------------------------------------------------------------
template<int MODE>
__global__ __launch_bounds__(256, 4) void gemm128_kernel(
        const unsigned short* __restrict__ A,
        const unsigned short* __restrict__ BT,
        const int* __restrict__ meta,
        const int* __restrict__ liveBt,
        const int* __restrict__ grpSrc,
        const int* __restrict__ grpOut,
        unsigned short* __restrict__ o_q,
        unsigned short* __restrict__ o_k,
        unsigned short* __restrict__ o_v,
        float* __restrict__ o_f) {
    constexpr int K     = (MODE == 2) ? 512 : 1024;
    constexpr int NSTEP = K / 32;                              // even
    constexpr int NTSH  = (MODE == 0) ? 2 : 3;                 // log2(N-tiles)

    int lim = (MODE == 1) ? meta[1] : meta[2];
    int L = lim << NTSH;
    int bid = blockIdx.x;
    if (bid >= L) return;
    int wg = xcd_swz(bid, L);
    int mt = wg >> NTSH;
    int nt = wg & ((1 << NTSH) - 1);
    int n0 = nt * 128;
    int t = threadIdx.x;
    int lane = t & 63, wid = t >> 6;
    int lr = lane & 15, lg = lane >> 4;
    int wm = wid >> 1, wn = wid & 1;

    __shared__ __align__(16) unsigned short As[2][4096];   // 2 x 128x32
    __shared__ __align__(16) unsigned short Bs[2][4096];

    // staging pointers: issue (wid,j) covers tile rows (wid*2+j)*16..+16;
    // this lane covers row R, 16B slot (lane&3).
    const unsigned short* aptr[2];
    const unsigned short* bptr[2];
    int grp = wid >> 1;                                    // R>>6 for both j
    #pragma unroll
    for (int j = 0; j < 2; j++) {
        int R   = (wid * 2 + j) * 16 + (lane >> 2);        // row in 128-tile
        int rin = R & 63;                                  // row in 64-group
        size_t srow;
        if (MODE == 0) {
            int bt = liveBt[2 * mt + grp];
            srow = (size_t)bt * NKEY_ + 256 + rin;
        } else if (MODE == 1) {
            srow = (size_t)grpSrc[2 * mt + grp] + rin;
        } else {
            int bt = liveBt[2 * mt + grp];
            srow = (size_t)bt * 64 + rin;
        }
        aptr[j] = A  + srow * K + (lane & 3) * 8;
        bptr[j] = BT + (size_t)(n0 + R) * K + (lane & 3) * 8;
    }

    f32x4 acc[4][4];
    #pragma unroll
    for (int i = 0; i < 4; i++)
        #pragma unroll
        for (int j = 0; j < 4; j++) acc[i][j] = (f32x4){0.f, 0.f, 0.f, 0.f};

    auto stage = [&](int buf) {
        #pragma unroll
        for (int j = 0; j < 2; j++) {
            async16(&As[buf][(wid * 2 + j) * 512], aptr[j]);
            async16(&Bs[buf][(wid * 2 + j) * 512], bptr[j]);
            aptr[j] += 32; bptr[j] += 32;
        }
    };
    auto compute = [&](int buf) {
        short8 af[4], bf[4];
        #pragma unroll
        for (int mi = 0; mi < 4; mi++)
            af[mi] = *reinterpret_cast<const short8*>(
                &As[buf][(wm * 64 + mi * 16 + lr) * 32 + lg * 8]);
        #pragma unroll
        for (int ni = 0; ni < 4; ni++)
            bf[ni] = *reinterpret_cast<const short8*>(
                &Bs[buf][(wn * 64 + ni * 16 + lr) * 32 + lg * 8]);
        #pragma unroll
        for (int mi = 0; mi < 4; mi++)
            #pragma unroll
            for (int ni = 0; ni < 4; ni++)
                acc[mi][ni] = __builtin_amdgcn_mfma_f32_16x16x32_bf16(
                    af[mi], bf[ni], acc[mi][ni], 0, 0, 0);
    };

    #define FULL_STEP(CUR)                                              \
        stage((CUR) ^ 1);                                               \
        asm volatile("s_waitcnt vmcnt(4)" ::: "memory");                \
        __builtin_amdgcn_s_barrier();                                   \
        compute(CUR);                                                   \
        asm volatile("s_waitcnt lgkmcnt(0)" ::: "memory");              \
        __builtin_amdgcn_s_barrier();

    stage(0);
    #pragma unroll 1
    for (int ks2 = 0; ks2 < NSTEP / 2 - 1; ks2++) {
        FULL_STEP(0)
        FULL_STEP(1)
    }
    FULL_STEP(0)
    asm volatile("s_waitcnt vmcnt(0)" ::: "memory");
    __builtin_amdgcn_s_barrier();
    compute(1);
    #undef FULL_STEP

    #pragma unroll
    for (int mi = 0; mi < 4; mi++)
        #pragma unroll
        for (int ni = 0; ni < 4; ni++) {
            int rr = mi * 16 + lg * 4;                     // row in 64-group
            int c  = n0 + wn * 64 + ni * 16 + lr;
            if (MODE == 0) {
                int bt = liveBt[2 * mt + wm];
                #pragma unroll
                for (int r = 0; r < 4; r++)
                    o_q[((size_t)bt * 64 + rr + r) * 512 + c] =
                        f2bf(acc[mi][ni][r] * 0.125f);
            } else if (MODE == 1) {
                int enc = grpOut[2 * mt + wm];
                int bt = enc >> 16, krow = (enc & 0xffff) + rr;
                if (c < 512) {
                    #pragma unroll
                    for (int r = 0; r < 4; r++)
                        o_k[((size_t)bt * NKEY_ + krow + r) * 512 + c] =
                            f2bf(acc[mi][ni][r]);
                } else {
                    ushort4 pv;
                    pv.x = f2bf(acc[mi][ni][0]); pv.y = f2bf(acc[mi][ni][1]);
                    pv.z = f2bf(acc[mi][ni][2]); pv.w = f2bf(acc[mi][ni][3]);
                    *reinterpret_cast<ushort4*>(
                        o_v + ((size_t)bt * 512 + (c - 512)) * NKEY_ + krow) = pv;
                }
            } else {
                int bt = liveBt[2 * mt + wm];
                #pragma unroll
                for (int r = 0; r < 4; r++)
                    o_f[((size_t)bt * 64 + rr + r) * 1024 + c] = acc[mi][ni][r];
            }
        }
}

// ---------------------------------------------------------------------------
// zero-fill d_out rows of masked (b,t)
// ---------------------------------------------------------------------------
__global__ __launch_bounds__(256) void zero_kernel(const int* __restrict__ maskN,
                                                   float* __restrict__ out) {
    int bt = blockIdx.x;
    if (maskN[bt]) return;
    float4* p = reinterpret_cast<float4*>(out + (size_t)bt * 65536);
    float4 z = make_float4(0.f, 0.f, 0.f, 0.f);
    #pragma unroll
    for (int k = 0; k < 64; k++) p[k * 256 + threadIdx.x] = z;
}

// ---------------------------------------------------------------------------
// fused attention per live (bt,h): sim = q @ k^T (64x320), softmax, attn @ v
// ---------------------------------------------------------------------------
__global__ __launch_bounds__(256) void attn_kernel(
        const unsigned short* __restrict__ q,
        const unsigned short* __restrict__ kbuf,
        const unsigned short* __restrict__ vbuf,   // vT [bt][512][320]
        const int* __restrict__ meta,
        const int* __restrict__ liveBt,
        unsigned short* __restrict__ ao) {
    int L = meta[0] << 3;
    int bid = blockIdx.x;
    if (bid >= L) return;
    int wg = xcd_swz(bid, L);
    int i = wg >> 3, h = wg & 7;
    int bt = liveBt[i];
    int t = threadIdx.x, w = t >> 6, lane = t & 63;
    int lr = lane & 15, lg = lane >> 4;
    __shared__ __align__(16) unsigned short attn_s[4][16][328];

    const unsigned short* qrow = q + ((size_t)bt * 64 + w * 16 + lr) * 512 + h * 64;
    short8 qa0 = *reinterpret_cast<const short8*>(qrow + lg * 8);
    short8 qa1 = *reinterpret_cast<const short8*>(qrow + 32 + lg * 8);

    f32x4 acc[20];
    #pragma unroll
    for (int i2 = 0; i2 < 20; i2++) acc[i2] = (f32x4){0.f, 0.f, 0.f, 0.f};

    const unsigned short* kb = kbuf + (size_t)bt * NKEY_ * 512 + h * 64;
    #pragma unroll
    for (int nt2 = 0; nt2 < 20; nt2++) {
        const unsigned short* krow = kb + (size_t)(nt2 * 16 + lr) * 512;
        short8 b0 = *reinterpret_cast<const short8*>(krow + lg * 8);
        short8 b1 = *reinterpret_cast<const short8*>(krow + 32 + lg * 8);
        acc[nt2] = __builtin_amdgcn_mfma_f32_16x16x32_bf16(qa0, b0, acc[nt2], 0, 0, 0);
        acc[nt2] = __builtin_amdgcn_mfma_f32_16x16x32_bf16(qa1, b1, acc[nt2], 0, 0, 0);
    }

    float mx[4], sm[4];
    #pragma unroll
    for (int r = 0; r < 4; r++) mx[r] = -1e30f;
    #pragma unroll
    for (int nt2 = 0; nt2 < 20; nt2++)
        #pragma unroll
        for (int r = 0; r < 4; r++) mx[r] = fmaxf(mx[r], acc[nt2][r]);
    #pragma unroll
    for (int r = 0; r < 4; r++) {
        #pragma unroll
        for (int off = 1; off < 16; off <<= 1)
            mx[r] = fmaxf(mx[r], __shfl_xor(mx[r], off));
        sm[r] = 0.f;
    }
    #pragma unroll
    for (int nt2 = 0; nt2 < 20; nt2++)
        #pragma unroll
        for (int r = 0; r < 4; r++) {
            float p = __expf(acc[nt2][r] - mx[r]);
            acc[nt2][r] = p;
            sm[r] += p;
        }
    #pragma unroll
    for (int r = 0; r < 4; r++) {
        #pragma unroll
        for (int off = 1; off < 16; off <<= 1)
            sm[r] += __shfl_xor(sm[r], off);
        sm[r] = 1.0f / sm[r];
    }
    #pragma unroll
    for (int nt2 = 0; nt2 < 20; nt2++)
        #pragma unroll
        for (int r = 0; r < 4; r++)
            attn_s[w][lg * 4 + r][nt2 * 16 + lr] = f2bf(acc[nt2][r] * sm[r]);
    __syncthreads();

    f32x4 o[4];
    #pragma unroll
    for (int i2 = 0; i2 < 4; i2++) o[i2] = (f32x4){0.f, 0.f, 0.f, 0.f};
    const unsigned short* vb = vbuf + (size_t)bt * 512 * NKEY_ + (size_t)h * 64 * NKEY_;
    #pragma unroll
    for (int kc = 0; kc < 10; kc++) {
        short8 pa = *reinterpret_cast<const short8*>(&attn_s[w][lr][kc * 32 + lg * 8]);
        #pragma unroll
        for (int ni = 0; ni < 4; ni++) {
            short8 vf = *reinterpret_cast<const short8*>(
                vb + (size_t)(ni * 16 + lr) * NKEY_ + kc * 32 + lg * 8);
            o[ni] = __builtin_amdgcn_mfma_f32_16x16x32_bf16(pa, vf, o[ni], 0, 0, 0);
        }
    }
    #pragma unroll
    for (int ni = 0; ni < 4; ni++)
        #pragma unroll
        for (int r = 0; r < 4; r++)
            ao[((size_t)bt * 64 + w * 16 + lg * 4 + r) * 512 + h * 64 + ni * 16 + lr] =
                f2bf(o[ni][r]);
}

// ---------------------------------------------------------------------------
extern "C" void kernel_launch(void* const* d_in, const int* in_sizes, int n_in,
                              void* d_out, int out_size, void* d_ws, size_t ws_size,
                              hipStream_t stream) {
    const float* x            = (const float*)d_in[0];
    const float* lat          = (const float*)d_in[1];
    const unsigned char* mraw = (const unsigned char*)d_in[2];
    const float* gm           = (const float*)d_in[3];
    const float* bm           = (const float*)d_in[4];
    const float* gl           = (const float*)d_in[5];
    const float* bl           = (const float*)d_in[6];
    const float* Wq           = (const float*)d_in[7];
    const float* Wkv          = (const float*)d_in[8];
    const float* Wo           = (const float*)d_in[9];
    float* out = (float*)d_out;

    char* ws = (char*)d_ws;
    int* maskN  = (int*)(ws + 0);          // 512 B
    int* meta   = (int*)(ws + 512);        // 64 B
    int* liveBt = (int*)(ws + 1024);       // 640 B
    int* grpSrc = (int*)(ws + 2048);       // ~2.6 KB
    int* grpOut = (int*)(ws + 5120);       // ~2.6 KB
    size_t off = 8192;
    unsigned short* WqT  = (unsigned short*)(ws + off); off += 1048576;   // 512*1024*2
    unsigned short* WkvT = (unsigned short*)(ws + off); off += 2097152;   // 1024*1024*2
    unsigned short* WoT  = (unsigned short*)(ws + off); off += 1048576;   // 1024*512*2
    unsigned short* kvin = (unsigned short*)(ws + off); off += 83886080;  // 128*320*1024*2
    unsigned short* qb   = (unsigned short*)(ws + off); off += 8388608;   // 128*64*512*2
    unsigned short* kb   = (unsigned short*)(ws + off); off += 41943040;  // 128*320*512*2
    unsigned short* vb   = (unsigned short*)(ws + off); off += 41943040;  // 128*512*320*2
    unsigned short* ab   = (unsigned short*)(ws + off); off += 8388608;   // 128*64*512*2

    hipLaunchKernelGGL(mask_kernel,  dim3(1),     dim3(64),  0, stream,
                       mraw, maskN, meta, liveBt, grpSrc, grpOut);
    hipLaunchKernelGGL(wprep_kernel, dim3(8192),  dim3(256), 0, stream,
                       Wq, Wkv, Wo, WqT, WkvT, WoT);
    hipLaunchKernelGGL(ln_kernel,    dim3(40960), dim3(256), 0, stream,
                       x, lat, gm, bm, gl, bl, maskN, kvin);
    hipLaunchKernelGGL((gemm128_kernel<0>), dim3(256),  dim3(256), 0, stream,
                       kvin, WqT,  meta, liveBt, grpSrc, grpOut, qb, kb, vb, out);
    hipLaunchKernelGGL((gemm128_kernel<1>), dim3(2560), dim3(256), 0, stream,
                       kvin, WkvT, meta, liveBt, grpSrc, grpOut, qb, kb, vb, out);
    hipLaunchKernelGGL(attn_kernel,         dim3(1024), dim3(256), 0, stream,
                       qb, kb, vb, meta, liveBt, ab);
    hipLaunchKernelGGL(zero_kernel,         dim3(128),  dim3(256), 0, stream,
                       maskN, out);
    hipLaunchKernelGGL((gemm128_kernel<2>), dim3(512),  dim3(256), 0, stream,
                       ab, WoT,  meta, liveBt, grpSrc, grpOut, qb, kb, vb, out);
}

// Round 13
// 151.230 us; speedup vs baseline: 1.5839x; 1.1731x over previous
//
#include <hip/hip_runtime.h>
#include <stdint.h>
#include <stddef.h>

#define B_      8
#define T_      16
#define NX_     256
#define NZ_     64
#define D_      1024
#define HEADS_  8
#define DHEAD_  64
#define INNER_  512
#define NKEY_   320          // NX_ + NZ_
#define NBT_    128          // B_*T_

typedef __attribute__((ext_vector_type(8))) short     short8;
typedef __attribute__((ext_vector_type(4))) float     f32x4;
typedef __attribute__((ext_vector_type(8))) unsigned short u16x8;

__device__ __forceinline__ unsigned short f2bf(float f) {
    union { float f; unsigned int u; } v; v.f = f;
    unsigned int u = v.u;
    return (unsigned short)((u + 0x7fffu + ((u >> 16) & 1u)) >> 16);
}

__device__ __forceinline__ void async16(unsigned short* lds, const unsigned short* g) {
    __builtin_amdgcn_global_load_lds(
        (const __attribute__((address_space(1))) void*)g,
        (__attribute__((address_space(3))) void*)lds, 16, 0, 0);
}

// bijective XCD-chunked swizzle over L live blocks (m204)
__device__ __forceinline__ int xcd_swz(int bid, int L) {
    int q = L >> 3, r = L & 7;
    int xcd = bid & 7, idx = bid >> 3;
    return (xcd < r ? xcd * (q + 1) : r * (q + 1) + (xcd - r) * q) + idx;
}

// ---------------------------------------------------------------------------
// prep: blocks 0..8191 = weight transpose f32->bf16; block 8192 = mask
// normalization + WAVE-PARALLEL live-compaction (ballot/popc prefix; the old
// serial lane-0 loop cost ~10us of dependent L2 round-trips).
// meta[0]=nliveBt, meta[1]=#kv M-tiles, meta[2]=#bt-pair tiles.
// ---------------------------------------------------------------------------
__global__ __launch_bounds__(256) void prep_kernel(
        const float* __restrict__ Wq, const float* __restrict__ Wkv,
        const float* __restrict__ Wo, const unsigned char* __restrict__ mraw,
        unsigned short* __restrict__ WqT, unsigned short* __restrict__ WkvT,
        unsigned short* __restrict__ WoT,
        int* __restrict__ maskN, int* __restrict__ meta,
        int* __restrict__ liveBt, int* __restrict__ grpSrc,
        int* __restrict__ grpOut) {
    if (blockIdx.x == 8192) {
        int l = threadIdx.x;
        if (l >= 64) return;                 // one wave does everything
        unsigned char b0 = mraw[l];
        unsigned char b1 = mraw[l + 64];
        bool nz = ((l & 3) != 0 && b0 != 0) || (((l + 64) & 3) != 0 && b1 != 0);
        unsigned long long ball = __ballot(nz ? 1 : 0);
        bool isBool = (ball != 0ull);
        int v0, v1;
        if (isBool) { v0 = b0; v1 = b1; }
        else        { v0 = mraw[4 * l]; v1 = mraw[4 * (l + 64)]; }
        v0 = v0 ? 1 : 0; v1 = v1 ? 1 : 0;
        maskN[l]      = v0;
        maskN[l + 64] = v1;
        unsigned long long B0 = __ballot(v0), B1 = __ballot(v1);
        int n0 = __popcll(B0);
        int nl = n0 + __popcll(B1);
        unsigned long long below = (1ull << l) - 1ull;
        if (v0) {
            int p = __popcll(B0 & below);
            liveBt[p] = l;
            #pragma unroll
            for (int g = 0; g < 5; g++) {
                grpSrc[5 * p + g] = l * NKEY_ + g * 64;
                grpOut[5 * p + g] = (l << 16) | (g * 64);
            }
        }
        if (v1) {
            int p = n0 + __popcll(B1 & below);
            int bt = l + 64;
            liveBt[p] = bt;
            #pragma unroll
            for (int g = 0; g < 5; g++) {
                grpSrc[5 * p + g] = bt * NKEY_ + g * 64;
                grpOut[5 * p + g] = (bt << 16) | (g * 64);
            }
        }
        if (l == 0) {
            // padding computed arithmetically (no readback of other lanes)
            int lastBt = 0;
            if (B1) lastBt = 64 + (63 - __clzll(B1));
            else if (B0) lastBt = 63 - __clzll(B0);
            int ng = 5 * nl;
            if (nl & 1) liveBt[nl] = lastBt;
            if (ng & 1) { grpSrc[ng] = lastBt * NKEY_ + 256;
                          grpOut[ng] = (lastBt << 16) | 256; }
            meta[0] = nl;
            meta[1] = (ng + 1) >> 1;
            meta[2] = (nl + 1) >> 1;
        }
        return;
    }
    size_t id = (size_t)blockIdx.x * 256 + threadIdx.x;
    if (id < 524288) {                       // WqT[512][1024] <- Wq[1024][512]
        int n = (int)(id >> 10), k = (int)(id & 1023);
        WqT[id] = f2bf(Wq[(size_t)k * 512 + n]);
    } else if (id < 524288 + 1048576) {      // WkvT[1024][1024] <- Wkv[1024][1024]
        size_t j = id - 524288;
        int n = (int)(j >> 10), k = (int)(j & 1023);
        WkvT[j] = f2bf(Wkv[(size_t)k * 1024 + n]);
    } else {                                 // WoT[1024][512] <- Wo[512][1024]
        size_t j = id - 1572864;
        int n = (int)(j >> 9), k = (int)(j & 511);
        WoT[j] = f2bf(Wo[(size_t)k * 1024 + n]);
    }
}

// ---------------------------------------------------------------------------
// LayerNorm rows of x (32768) and latents (8192) -> bf16 packed kvin
// ---------------------------------------------------------------------------
__global__ __launch_bounds__(256) void ln_kernel(
        const float* __restrict__ x, const float* __restrict__ lat,
        const float* __restrict__ gm, const float* __restrict__ bm,
        const float* __restrict__ gl, const float* __restrict__ bl,
        const int* __restrict__ maskN,
        unsigned short* __restrict__ kvin) {
    int row = blockIdx.x;
    const float* src; unsigned short* dst; const float* g; const float* b;
    int bt;
    if (row < NBT_ * NX_) {
        bt = row >> 8;
        src = x + (size_t)row * D_;
        dst = kvin + ((size_t)bt * NKEY_ + (row & 255)) * D_;
        g = gm; b = bm;
    } else {
        int r = row - NBT_ * NX_;
        bt = r >> 6;
        src = lat + (size_t)r * D_;
        dst = kvin + ((size_t)bt * NKEY_ + 256 + (r & 63)) * D_;
        g = gl; b = bl;
    }
    if (!maskN[bt]) return;                  // masked (b,t): values never read
    int t = threadIdx.x;
    float4 v = reinterpret_cast<const float4*>(src)[t];
    float s  = v.x + v.y + v.z + v.w;
    float sq = v.x * v.x + v.y * v.y + v.z * v.z + v.w * v.w;
    #pragma unroll
    for (int off = 32; off > 0; off >>= 1) {
        s  += __shfl_down(s, off);
        sq += __shfl_down(sq, off);
    }
    __shared__ float red[8];
    int wid = t >> 6;
    if ((t & 63) == 0) { red[wid] = s; red[4 + wid] = sq; }
    __syncthreads();
    float stot = red[0] + red[1] + red[2] + red[3];
    float qtot = red[4] + red[5] + red[6] + red[7];
    float mean = stot * (1.0f / 1024.0f);
    float var  = qtot * (1.0f / 1024.0f) - mean * mean;
    float rstd = rsqrtf(var + 1e-5f);
    float4 gv = reinterpret_cast<const float4*>(g)[t];
    float4 bv = reinterpret_cast<const float4*>(b)[t];
    ushort4 o;
    o.x = f2bf((v.x - mean) * rstd * gv.x + bv.x);
    o.y = f2bf((v.y - mean) * rstd * gv.y + bv.y);
    o.z = f2bf((v.z - mean) * rstd * gv.z + bv.z);
    o.w = f2bf((v.w - mean) * rstd * gv.w + bv.w);
    *reinterpret_cast<ushort4*>(dst + 4 * t) = o;
}

// ---------------------------------------------------------------------------
// Compacted dbuf GEMM, BK=32 high-residency (R12-proven): 128x128, 4 waves,
// 32 KB LDS -> 4 blocks/CU, counted vmcnt(4). Per-lane mapping derived from
// the wave-uniform gload_lds rule: issue (wid,j) -> LDS base (wid*2+j)*512;
// lane l covers row R=(wid*2+j)*16+(l>>2), 16B slot l&3.
// MODE 0: q  = zn(live) @ WqT,  *0.125, bf16
// MODE 1: kv = kvin(live grps) @ WkvT -> k[bt][320][512], vT[bt][512][320]
// MODE 2: out = ao(live) @ WoT, f32 (live rows; dead rows zeroed in attn tail)
// ---------------------------------------------------------------------------
template<int MODE>
__global__ __launch_bounds__(256, 4) void gemm128_kernel(
        const unsigned short* __restrict__ A,
        const unsigned short* __restrict__ BT,
        const int* __restrict__ meta,
        const int* __restrict__ liveBt,
        const int* __restrict__ grpSrc,
        const int* __restrict__ grpOut,
        unsigned short* __restrict__ o_q,
        unsigned short* __restrict__ o_k,
        unsigned short* __restrict__ o_v,
        float* __restrict__ o_f) {
    constexpr int K     = (MODE == 2) ? 512 : 1024;
    constexpr int NSTEP = K / 32;                              // even
    constexpr int NTSH  = (MODE == 0) ? 2 : 3;                 // log2(N-tiles)

    int lim = (MODE == 1) ? meta[1] : meta[2];
    int L = lim << NTSH;
    int bid = blockIdx.x;
    if (bid >= L) return;
    int wg = xcd_swz(bid, L);
    int mt = wg >> NTSH;
    int nt = wg & ((1 << NTSH) - 1);
    int n0 = nt * 128;
    int t = threadIdx.x;
    int lane = t & 63, wid = t >> 6;
    int lr = lane & 15, lg = lane >> 4;
    int wm = wid >> 1, wn = wid & 1;

    __shared__ __align__(16) unsigned short As[2][4096];   // 2 x 128x32
    __shared__ __align__(16) unsigned short Bs[2][4096];

    const unsigned short* aptr[2];
    const unsigned short* bptr[2];
    int grp = wid >> 1;                                    // R>>6 for both j
    #pragma unroll
    for (int j = 0; j < 2; j++) {
        int R   = (wid * 2 + j) * 16 + (lane >> 2);        // row in 128-tile
        int rin = R & 63;                                  // row in 64-group
        size_t srow;
        if (MODE == 0) {
            int bt = liveBt[2 * mt + grp];
            srow = (size_t)bt * NKEY_ + 256 + rin;
        } else if (MODE == 1) {
            srow = (size_t)grpSrc[2 * mt + grp] + rin;
        } else {
            int bt = liveBt[2 * mt + grp];
            srow = (size_t)bt * 64 + rin;
        }
        aptr[j] = A  + srow * K + (lane & 3) * 8;
        bptr[j] = BT + (size_t)(n0 + R) * K + (lane & 3) * 8;
    }

    f32x4 acc[4][4];
    #pragma unroll
    for (int i = 0; i < 4; i++)
        #pragma unroll
        for (int j = 0; j < 4; j++) acc[i][j] = (f32x4){0.f, 0.f, 0.f, 0.f};

    auto stage = [&](int buf) {
        #pragma unroll
        for (int j = 0; j < 2; j++) {
            async16(&As[buf][(wid * 2 + j) * 512], aptr[j]);
            async16(&Bs[buf][(wid * 2 + j) * 512], bptr[j]);
            aptr[j] += 32; bptr[j] += 32;
        }
    };
    auto compute = [&](int buf) {
        short8 af[4], bf[4];
        #pragma unroll
        for (int mi = 0; mi < 4; mi++)
            af[mi] = *reinterpret_cast<const short8*>(
                &As[buf][(wm * 64 + mi * 16 + lr) * 32 + lg * 8]);
        #pragma unroll
        for (int ni = 0; ni < 4; ni++)
            bf[ni] = *reinterpret_cast<const short8*>(
                &Bs[buf][(wn * 64 + ni * 16 + lr) * 32 + lg * 8]);
        #pragma unroll
        for (int mi = 0; mi < 4; mi++)
            #pragma unroll
            for (int ni = 0; ni < 4; ni++)
                acc[mi][ni] = __builtin_amdgcn_mfma_f32_16x16x32_bf16(
                    af[mi], bf[ni], acc[mi][ni], 0, 0, 0);
    };

    #define FULL_STEP(CUR)                                              \
        stage((CUR) ^ 1);                                               \
        asm volatile("s_waitcnt vmcnt(4)" ::: "memory");                \
        __builtin_amdgcn_s_barrier();                                   \
        compute(CUR);                                                   \
        asm volatile("s_waitcnt lgkmcnt(0)" ::: "memory");              \
        __builtin_amdgcn_s_barrier();

    stage(0);
    #pragma unroll 1
    for (int ks2 = 0; ks2 < NSTEP / 2 - 1; ks2++) {
        FULL_STEP(0)
        FULL_STEP(1)
    }
    FULL_STEP(0)
    asm volatile("s_waitcnt vmcnt(0)" ::: "memory");
    __builtin_amdgcn_s_barrier();
    compute(1);
    #undef FULL_STEP

    #pragma unroll
    for (int mi = 0; mi < 4; mi++)
        #pragma unroll
        for (int ni = 0; ni < 4; ni++) {
            int rr = mi * 16 + lg * 4;                     // row in 64-group
            int c  = n0 + wn * 64 + ni * 16 + lr;
            if (MODE == 0) {
                int bt = liveBt[2 * mt + wm];
                #pragma unroll
                for (int r = 0; r < 4; r++)
                    o_q[((size_t)bt * 64 + rr + r) * 512 + c] =
                        f2bf(acc[mi][ni][r] * 0.125f);
            } else if (MODE == 1) {
                int enc = grpOut[2 * mt + wm];
                int bt = enc >> 16, krow = (enc & 0xffff) + rr;
                if (c < 512) {
                    #pragma unroll
                    for (int r = 0; r < 4; r++)
                        o_k[((size_t)bt * NKEY_ + krow + r) * 512 + c] =
                            f2bf(acc[mi][ni][r]);
                } else {
                    ushort4 pv;
                    pv.x = f2bf(acc[mi][ni][0]); pv.y = f2bf(acc[mi][ni][1]);
                    pv.z = f2bf(acc[mi][ni][2]); pv.w = f2bf(acc[mi][ni][3]);
                    *reinterpret_cast<ushort4*>(
                        o_v + ((size_t)bt * 512 + (c - 512)) * NKEY_ + krow) = pv;
                }
            } else {
                int bt = liveBt[2 * mt + wm];
                #pragma unroll
                for (int r = 0; r < 4; r++)
                    o_f[((size_t)bt * 64 + rr + r) * 1024 + c] = acc[mi][ni][r];
            }
        }
}

// ---------------------------------------------------------------------------
// fused attention per live (bt,h) + zero-fill tail (blocks 1024..1151 zero
// the d_out rows of masked bt, replacing the separate zero_kernel launch).
// ---------------------------------------------------------------------------
__global__ __launch_bounds__(256) void attn_kernel(
        const unsigned short* __restrict__ q,
        const unsigned short* __restrict__ kbuf,
        const unsigned short* __restrict__ vbuf,   // vT [bt][512][320]
        const int* __restrict__ meta,
        const int* __restrict__ liveBt,
        const int* __restrict__ maskN,
        unsigned short* __restrict__ ao,
        float* __restrict__ out_f) {
    int bid = blockIdx.x;
    if (bid >= 1024) {                             // zero-fill tail
        int bt = bid - 1024;
        if (maskN[bt]) return;
        float4* p = reinterpret_cast<float4*>(out_f + (size_t)bt * 65536);
        float4 z = make_float4(0.f, 0.f, 0.f, 0.f);
        #pragma unroll
        for (int k = 0; k < 64; k++) p[k * 256 + threadIdx.x] = z;
        return;
    }
    int L = meta[0] << 3;
    if (bid >= L) return;
    int wg = xcd_swz(bid, L);
    int i = wg >> 3, h = wg & 7;
    int bt = liveBt[i];
    int t = threadIdx.x, w = t >> 6, lane = t & 63;
    int lr = lane & 15, lg = lane >> 4;
    __shared__ __align__(16) unsigned short attn_s[4][16][328];

    const unsigned short* qrow = q + ((size_t)bt * 64 + w * 16 + lr) * 512 + h * 64;
    short8 qa0 = *reinterpret_cast<const short8*>(qrow + lg * 8);
    short8 qa1 = *reinterpret_cast<const short8*>(qrow + 32 + lg * 8);

    f32x4 acc[20];
    #pragma unroll
    for (int i2 = 0; i2 < 20; i2++) acc[i2] = (f32x4){0.f, 0.f, 0.f, 0.f};

    const unsigned short* kb = kbuf + (size_t)bt * NKEY_ * 512 + h * 64;
    #pragma unroll
    for (int nt2 = 0; nt2 < 20; nt2++) {
        const unsigned short* krow = kb + (size_t)(nt2 * 16 + lr) * 512;
        short8 b0 = *reinterpret_cast<const short8*>(krow + lg * 8);
        short8 b1 = *reinterpret_cast<const short8*>(krow + 32 + lg * 8);
        acc[nt2] = __builtin_amdgcn_mfma_f32_16x16x32_bf16(qa0, b0, acc[nt2], 0, 0, 0);
        acc[nt2] = __builtin_amdgcn_mfma_f32_16x16x32_bf16(qa1, b1, acc[nt2], 0, 0, 0);
    }

    float mx[4], sm[4];
    #pragma unroll
    for (int r = 0; r < 4; r++) mx[r] = -1e30f;
    #pragma unroll
    for (int nt2 = 0; nt2 < 20; nt2++)
        #pragma unroll
        for (int r = 0; r < 4; r++) mx[r] = fmaxf(mx[r], acc[nt2][r]);
    #pragma unroll
    for (int r = 0; r < 4; r++) {
        #pragma unroll
        for (int off = 1; off < 16; off <<= 1)
            mx[r] = fmaxf(mx[r], __shfl_xor(mx[r], off));
        sm[r] = 0.f;
    }
    #pragma unroll
    for (int nt2 = 0; nt2 < 20; nt2++)
        #pragma unroll
        for (int r = 0; r < 4; r++) {
            float p = __expf(acc[nt2][r] - mx[r]);
            acc[nt2][r] = p;
            sm[r] += p;
        }
    #pragma unroll
    for (int r = 0; r < 4; r++) {
        #pragma unroll
        for (int off = 1; off < 16; off <<= 1)
            sm[r] += __shfl_xor(sm[r], off);
        sm[r] = 1.0f / sm[r];
    }
    #pragma unroll
    for (int nt2 = 0; nt2 < 20; nt2++)
        #pragma unroll
        for (int r = 0; r < 4; r++)
            attn_s[w][lg * 4 + r][nt2 * 16 + lr] = f2bf(acc[nt2][r] * sm[r]);
    __syncthreads();

    f32x4 o[4];
    #pragma unroll
    for (int i2 = 0; i2 < 4; i2++) o[i2] = (f32x4){0.f, 0.f, 0.f, 0.f};
    const unsigned short* vb = vbuf + (size_t)bt * 512 * NKEY_ + (size_t)h * 64 * NKEY_;
    #pragma unroll
    for (int kc = 0; kc < 10; kc++) {
        short8 pa = *reinterpret_cast<const short8*>(&attn_s[w][lr][kc * 32 + lg * 8]);
        #pragma unroll
        for (int ni = 0; ni < 4; ni++) {
            short8 vf = *reinterpret_cast<const short8*>(
                vb + (size_t)(ni * 16 + lr) * NKEY_ + kc * 32 + lg * 8);
            o[ni] = __builtin_amdgcn_mfma_f32_16x16x32_bf16(pa, vf, o[ni], 0, 0, 0);
        }
    }
    #pragma unroll
    for (int ni = 0; ni < 4; ni++)
        #pragma unroll
        for (int r = 0; r < 4; r++)
            ao[((size_t)bt * 64 + w * 16 + lg * 4 + r) * 512 + h * 64 + ni * 16 + lr] =
                f2bf(o[ni][r]);
}

// ---------------------------------------------------------------------------
extern "C" void kernel_launch(void* const* d_in, const int* in_sizes, int n_in,
                              void* d_out, int out_size, void* d_ws, size_t ws_size,
                              hipStream_t stream) {
    const float* x            = (const float*)d_in[0];
    const float* lat          = (const float*)d_in[1];
    const unsigned char* mraw = (const unsigned char*)d_in[2];
    const float* gm           = (const float*)d_in[3];
    const float* bm           = (const float*)d_in[4];
    const float* gl           = (const float*)d_in[5];
    const float* bl           = (const float*)d_in[6];
    const float* Wq           = (const float*)d_in[7];
    const float* Wkv          = (const float*)d_in[8];
    const float* Wo           = (const float*)d_in[9];
    float* out = (float*)d_out;

    char* ws = (char*)d_ws;
    int* maskN  = (int*)(ws + 0);          // 512 B
    int* meta   = (int*)(ws + 512);        // 64 B
    int* liveBt = (int*)(ws + 1024);       // 640 B
    int* grpSrc = (int*)(ws + 2048);       // ~2.6 KB
    int* grpOut = (int*)(ws + 5120);       // ~2.6 KB
    size_t off = 8192;
    unsigned short* WqT  = (unsigned short*)(ws + off); off += 1048576;   // 512*1024*2
    unsigned short* WkvT = (unsigned short*)(ws + off); off += 2097152;   // 1024*1024*2
    unsigned short* WoT  = (unsigned short*)(ws + off); off += 1048576;   // 1024*512*2
    unsigned short* kvin = (unsigned short*)(ws + off); off += 83886080;  // 128*320*1024*2
    unsigned short* qb   = (unsigned short*)(ws + off); off += 8388608;   // 128*64*512*2
    unsigned short* kb   = (unsigned short*)(ws + off); off += 41943040;  // 128*320*512*2
    unsigned short* vb   = (unsigned short*)(ws + off); off += 41943040;  // 128*512*320*2
    unsigned short* ab   = (unsigned short*)(ws + off); off += 8388608;   // 128*64*512*2

    hipLaunchKernelGGL(prep_kernel, dim3(8193),  dim3(256), 0, stream,
                       Wq, Wkv, Wo, mraw, WqT, WkvT, WoT,
                       maskN, meta, liveBt, grpSrc, grpOut);
    hipLaunchKernelGGL(ln_kernel,   dim3(40960), dim3(256), 0, stream,
                       x, lat, gm, bm, gl, bl, maskN, kvin);
    hipLaunchKernelGGL((gemm128_kernel<0>), dim3(256),  dim3(256), 0, stream,
                       kvin, WqT,  meta, liveBt, grpSrc, grpOut, qb, kb, vb, out);
    hipLaunchKernelGGL((gemm128_kernel<1>), dim3(2560), dim3(256), 0, stream,
                       kvin, WkvT, meta, liveBt, grpSrc, grpOut, qb, kb, vb, out);
    hipLaunchKernelGGL(attn_kernel,         dim3(1152), dim3(256), 0, stream,
                       qb, kb, vb, meta, liveBt, maskN, ab, out);
    hipLaunchKernelGGL((gemm128_kernel<2>), dim3(512),  dim3(256), 0, stream,
                       ab, WoT,  meta, liveBt, grpSrc, grpOut, qb, kb, vb, out);
}

// Round 14
// 142.047 us; speedup vs baseline: 1.6863x; 1.0646x over previous
//
#include <hip/hip_runtime.h>
#include <stdint.h>
#include <stddef.h>

#define B_      8
#define T_      16
#define NX_     256
#define NZ_     64
#define D_      1024
#define HEADS_  8
#define DHEAD_  64
#define INNER_  512
#define NKEY_   320          // NX_ + NZ_
#define NBT_    128          // B_*T_

typedef __attribute__((ext_vector_type(8))) short     short8;
typedef __attribute__((ext_vector_type(4))) float     f32x4;

__device__ __forceinline__ unsigned short f2bf(float f) {
    union { float f; unsigned int u; } v; v.f = f;
    unsigned int u = v.u;
    return (unsigned short)((u + 0x7fffu + ((u >> 16) & 1u)) >> 16);
}

__device__ __forceinline__ void async16(unsigned short* lds, const unsigned short* g) {
    __builtin_amdgcn_global_load_lds(
        (const __attribute__((address_space(1))) void*)g,
        (__attribute__((address_space(3))) void*)lds, 16, 0, 0);
}

// bijective XCD-chunked swizzle over L live blocks (m204)
__device__ __forceinline__ int xcd_swz(int bid, int L) {
    int q = L >> 3, r = L & 7;
    int xcd = bid & 7, idx = bid >> 3;
    return (xcd < r ? xcd * (q + 1) : r * (q + 1) + (xcd - r) * q) + idx;
}

// ---------------------------------------------------------------------------
// fused prep + LN (one launch; prep's L2-bound transpose hides under LN's
// HBM stream). blocks 0..8191: weight transpose f32->bf16. block 8192:
// mask normalization + wave-parallel compaction lists. blocks 8193..49152:
// LayerNorm rows -> kvin (each block derives its own bt-liveness inline
// from mraw -- no dependence on block 8192).
// ---------------------------------------------------------------------------
__global__ __launch_bounds__(256) void prep_ln_kernel(
        const float* __restrict__ Wq, const float* __restrict__ Wkv,
        const float* __restrict__ Wo, const unsigned char* __restrict__ mraw,
        const float* __restrict__ x, const float* __restrict__ lat,
        const float* __restrict__ gm, const float* __restrict__ bm,
        const float* __restrict__ gl, const float* __restrict__ bl,
        unsigned short* __restrict__ WqT, unsigned short* __restrict__ WkvT,
        unsigned short* __restrict__ WoT, unsigned short* __restrict__ kvin,
        int* __restrict__ maskN, int* __restrict__ meta,
        int* __restrict__ liveBt, int* __restrict__ grpSrc,
        int* __restrict__ grpOut) {
    int bid = blockIdx.x;
    if (bid < 8192) {                        // ---- weight transpose
        size_t id = (size_t)bid * 256 + threadIdx.x;
        if (id < 524288) {                   // WqT[512][1024] <- Wq[1024][512]
            int n = (int)(id >> 10), k = (int)(id & 1023);
            WqT[id] = f2bf(Wq[(size_t)k * 512 + n]);
        } else if (id < 524288 + 1048576) {  // WkvT[1024][1024]
            size_t j = id - 524288;
            int n = (int)(j >> 10), k = (int)(j & 1023);
            WkvT[j] = f2bf(Wkv[(size_t)k * 1024 + n]);
        } else {                             // WoT[1024][512]
            size_t j = id - 1572864;
            int n = (int)(j >> 9), k = (int)(j & 511);
            WoT[j] = f2bf(Wo[(size_t)k * 1024 + n]);
        }
        return;
    }
    if (bid == 8192) {                       // ---- mask + compaction lists
        int l = threadIdx.x;
        if (l >= 64) return;
        unsigned char b0 = mraw[l];
        unsigned char b1 = mraw[l + 64];
        bool nz = ((l & 3) != 0 && b0 != 0) || (((l + 64) & 3) != 0 && b1 != 0);
        unsigned long long ball = __ballot(nz ? 1 : 0);
        bool isBool = (ball != 0ull);
        int v0, v1;
        if (isBool) { v0 = b0; v1 = b1; }
        else        { v0 = mraw[4 * l]; v1 = mraw[4 * (l + 64)]; }
        v0 = v0 ? 1 : 0; v1 = v1 ? 1 : 0;
        maskN[l]      = v0;
        maskN[l + 64] = v1;
        unsigned long long B0 = __ballot(v0), B1 = __ballot(v1);
        int n0 = __popcll(B0);
        int nl = n0 + __popcll(B1);
        unsigned long long below = (1ull << l) - 1ull;
        if (v0) {
            int p = __popcll(B0 & below);
            liveBt[p] = l;
            #pragma unroll
            for (int g = 0; g < 5; g++) {
                grpSrc[5 * p + g] = l * NKEY_ + g * 64;
                grpOut[5 * p + g] = (l << 16) | (g * 64);
            }
        }
        if (v1) {
            int p = n0 + __popcll(B1 & below);
            int bt = l + 64;
            liveBt[p] = bt;
            #pragma unroll
            for (int g = 0; g < 5; g++) {
                grpSrc[5 * p + g] = bt * NKEY_ + g * 64;
                grpOut[5 * p + g] = (bt << 16) | (g * 64);
            }
        }
        if (l == 0) {
            int lastBt = 0;
            if (B1) lastBt = 64 + (63 - __clzll(B1));
            else if (B0) lastBt = 63 - __clzll(B0);
            int ng = 5 * nl;
            if (nl & 1) liveBt[nl] = lastBt;
            if (ng & 1) { grpSrc[ng] = lastBt * NKEY_ + 256;
                          grpOut[ng] = (lastBt << 16) | 256; }
            meta[0] = nl;
            meta[1] = (ng + 1) >> 1;
            meta[2] = (nl + 1) >> 1;
        }
        return;
    }
    // ---- LayerNorm
    int row = bid - 8193;
    const float* src; unsigned short* dst; const float* g; const float* b;
    int bt;
    if (row < NBT_ * NX_) {
        bt = row >> 8;
        src = x + (size_t)row * D_;
        dst = kvin + ((size_t)bt * NKEY_ + (row & 255)) * D_;
        g = gm; b = bm;
    } else {
        int r = row - NBT_ * NX_;
        bt = r >> 6;
        src = lat + (size_t)r * D_;
        dst = kvin + ((size_t)bt * NKEY_ + 256 + (r & 63)) * D_;
        g = gl; b = bl;
    }
    int t = threadIdx.x;
    // inline liveness for this block's bt (no dependence on block 8192)
    __shared__ int liveFlag;
    if (t < 64) {
        unsigned char c0 = mraw[t];
        unsigned char c1 = mraw[t + 64];
        bool nz = ((t & 3) != 0 && c0 != 0) || (((t + 64) & 3) != 0 && c1 != 0);
        unsigned long long ball = __ballot(nz ? 1 : 0);
        bool isBool = (ball != 0ull);
        if (t == 0) {
            int v = isBool ? mraw[bt] : mraw[4 * bt];
            liveFlag = v ? 1 : 0;
        }
    }
    __syncthreads();
    if (!liveFlag) return;
    float4 v = reinterpret_cast<const float4*>(src)[t];
    float s  = v.x + v.y + v.z + v.w;
    float sq = v.x * v.x + v.y * v.y + v.z * v.z + v.w * v.w;
    #pragma unroll
    for (int off = 32; off > 0; off >>= 1) {
        s  += __shfl_down(s, off);
        sq += __shfl_down(sq, off);
    }
    __shared__ float red[8];
    int wid = t >> 6;
    if ((t & 63) == 0) { red[wid] = s; red[4 + wid] = sq; }
    __syncthreads();
    float stot = red[0] + red[1] + red[2] + red[3];
    float qtot = red[4] + red[5] + red[6] + red[7];
    float mean = stot * (1.0f / 1024.0f);
    float var  = qtot * (1.0f / 1024.0f) - mean * mean;
    float rstd = rsqrtf(var + 1e-5f);
    float4 gv = reinterpret_cast<const float4*>(g)[t];
    float4 bv = reinterpret_cast<const float4*>(b)[t];
    ushort4 o;
    o.x = f2bf((v.x - mean) * rstd * gv.x + bv.x);
    o.y = f2bf((v.y - mean) * rstd * gv.y + bv.y);
    o.z = f2bf((v.z - mean) * rstd * gv.z + bv.z);
    o.w = f2bf((v.w - mean) * rstd * gv.w + bv.w);
    *reinterpret_cast<ushort4*>(dst + 4 * t) = o;
}

// ---------------------------------------------------------------------------
// Compacted dbuf GEMM body (R12/R13-proven): 128x128, BK=32, 4 waves,
// 32 KB LDS (hoisted by caller), counted vmcnt(4). Per-lane mapping from the
// wave-uniform gload_lds rule: issue (wid,j) -> LDS base (wid*2+j)*512;
// lane l covers row R=(wid*2+j)*16+(l>>2), 16B slot l&3.
// ---------------------------------------------------------------------------
template<int MODE>
__device__ __forceinline__ void gemm128_body(
        int bid, unsigned short* As, unsigned short* Bs,
        const unsigned short* __restrict__ A,
        const unsigned short* __restrict__ BT,
        const int* __restrict__ meta,
        const int* __restrict__ liveBt,
        const int* __restrict__ grpSrc,
        const int* __restrict__ grpOut,
        unsigned short* __restrict__ o_q,
        unsigned short* __restrict__ o_k,
        unsigned short* __restrict__ o_v,
        float* __restrict__ o_f) {
    constexpr int K     = (MODE == 2) ? 512 : 1024;
    constexpr int NSTEP = K / 32;                              // even
    constexpr int NTSH  = (MODE == 0) ? 2 : 3;                 // log2(N-tiles)

    int lim = (MODE == 1) ? meta[1] : meta[2];
    int L = lim << NTSH;
    if (bid >= L) return;
    int wg = xcd_swz(bid, L);
    int mt = wg >> NTSH;
    int nt = wg & ((1 << NTSH) - 1);
    int n0 = nt * 128;
    int t = threadIdx.x;
    int lane = t & 63, wid = t >> 6;
    int lr = lane & 15, lg = lane >> 4;
    int wm = wid >> 1, wn = wid & 1;

    const unsigned short* aptr[2];
    const unsigned short* bptr[2];
    int grp = wid >> 1;                                    // R>>6 for both j
    #pragma unroll
    for (int j = 0; j < 2; j++) {
        int R   = (wid * 2 + j) * 16 + (lane >> 2);        // row in 128-tile
        int rin = R & 63;                                  // row in 64-group
        size_t srow;
        if (MODE == 0) {
            int bt = liveBt[2 * mt + grp];
            srow = (size_t)bt * NKEY_ + 256 + rin;
        } else if (MODE == 1) {
            srow = (size_t)grpSrc[2 * mt + grp] + rin;
        } else {
            int bt = liveBt[2 * mt + grp];
            srow = (size_t)bt * 64 + rin;
        }
        aptr[j] = A  + srow * K + (lane & 3) * 8;
        bptr[j] = BT + (size_t)(n0 + R) * K + (lane & 3) * 8;
    }

    f32x4 acc[4][4];
    #pragma unroll
    for (int i = 0; i < 4; i++)
        #pragma unroll
        for (int j = 0; j < 4; j++) acc[i][j] = (f32x4){0.f, 0.f, 0.f, 0.f};

    auto stage = [&](int buf) {
        #pragma unroll
        for (int j = 0; j < 2; j++) {
            async16(As + buf * 4096 + (wid * 2 + j) * 512, aptr[j]);
            async16(Bs + buf * 4096 + (wid * 2 + j) * 512, bptr[j]);
            aptr[j] += 32; bptr[j] += 32;
        }
    };
    auto compute = [&](int buf) {
        short8 af[4], bf[4];
        #pragma unroll
        for (int mi = 0; mi < 4; mi++)
            af[mi] = *reinterpret_cast<const short8*>(
                &As[buf * 4096 + (wm * 64 + mi * 16 + lr) * 32 + lg * 8]);
        #pragma unroll
        for (int ni = 0; ni < 4; ni++)
            bf[ni] = *reinterpret_cast<const short8*>(
                &Bs[buf * 4096 + (wn * 64 + ni * 16 + lr) * 32 + lg * 8]);
        #pragma unroll
        for (int mi = 0; mi < 4; mi++)
            #pragma unroll
            for (int ni = 0; ni < 4; ni++)
                acc[mi][ni] = __builtin_amdgcn_mfma_f32_16x16x32_bf16(
                    af[mi], bf[ni], acc[mi][ni], 0, 0, 0);
    };

    #define FULL_STEP(CUR)                                              \
        stage((CUR) ^ 1);                                               \
        asm volatile("s_waitcnt vmcnt(4)" ::: "memory");                \
        __builtin_amdgcn_s_barrier();                                   \
        compute(CUR);                                                   \
        asm volatile("s_waitcnt lgkmcnt(0)" ::: "memory");              \
        __builtin_amdgcn_s_barrier();

    stage(0);
    #pragma unroll 1
    for (int ks2 = 0; ks2 < NSTEP / 2 - 1; ks2++) {
        FULL_STEP(0)
        FULL_STEP(1)
    }
    FULL_STEP(0)
    asm volatile("s_waitcnt vmcnt(0)" ::: "memory");
    __builtin_amdgcn_s_barrier();
    compute(1);
    #undef FULL_STEP

    #pragma unroll
    for (int mi = 0; mi < 4; mi++)
        #pragma unroll
        for (int ni = 0; ni < 4; ni++) {
            int rr = mi * 16 + lg * 4;                     // row in 64-group
            int c  = n0 + wn * 64 + ni * 16 + lr;
            if (MODE == 0) {
                int bt = liveBt[2 * mt + wm];
                #pragma unroll
                for (int r = 0; r < 4; r++)
                    o_q[((size_t)bt * 64 + rr + r) * 512 + c] =
                        f2bf(acc[mi][ni][r] * 0.125f);
            } else if (MODE == 1) {
                int enc = grpOut[2 * mt + wm];
                int bt = enc >> 16, krow = (enc & 0xffff) + rr;
                if (c < 512) {
                    #pragma unroll
                    for (int r = 0; r < 4; r++)
                        o_k[((size_t)bt * NKEY_ + krow + r) * 512 + c] =
                            f2bf(acc[mi][ni][r]);
                } else {
                    ushort4 pv;
                    pv.x = f2bf(acc[mi][ni][0]); pv.y = f2bf(acc[mi][ni][1]);
                    pv.z = f2bf(acc[mi][ni][2]); pv.w = f2bf(acc[mi][ni][3]);
                    *reinterpret_cast<ushort4*>(
                        o_v + ((size_t)bt * 512 + (c - 512)) * NKEY_ + krow) = pv;
                }
            } else {
                int bt = liveBt[2 * mt + wm];
                #pragma unroll
                for (int r = 0; r < 4; r++)
                    o_f[((size_t)bt * 64 + rr + r) * 1024 + c] = acc[mi][ni][r];
            }
        }
}

// fused kv-GEMM (blocks 0..2559) + q-GEMM (blocks 2560..2815): independent
// consumers of kvin -> q's small grid rides along kv's launch.
__global__ __launch_bounds__(256, 4) void gemm_kvq_kernel(
        const unsigned short* __restrict__ kvin,
        const unsigned short* __restrict__ WkvT,
        const unsigned short* __restrict__ WqT,
        const int* __restrict__ meta,
        const int* __restrict__ liveBt,
        const int* __restrict__ grpSrc,
        const int* __restrict__ grpOut,
        unsigned short* __restrict__ o_q,
        unsigned short* __restrict__ o_k,
        unsigned short* __restrict__ o_v) {
    __shared__ __align__(16) unsigned short As[2 * 4096];
    __shared__ __align__(16) unsigned short Bs[2 * 4096];
    int bid = blockIdx.x;
    if (bid < 2560)
        gemm128_body<1>(bid, As, Bs, kvin, WkvT, meta, liveBt, grpSrc, grpOut,
                        o_q, o_k, o_v, (float*)0);
    else
        gemm128_body<0>(bid - 2560, As, Bs, kvin, WqT, meta, liveBt, grpSrc,
                        grpOut, o_q, o_k, o_v, (float*)0);
}

__global__ __launch_bounds__(256, 4) void gemm_out_kernel(
        const unsigned short* __restrict__ ab,
        const unsigned short* __restrict__ WoT,
        const int* __restrict__ meta,
        const int* __restrict__ liveBt,
        const int* __restrict__ grpSrc,
        const int* __restrict__ grpOut,
        float* __restrict__ o_f) {
    __shared__ __align__(16) unsigned short As[2 * 4096];
    __shared__ __align__(16) unsigned short Bs[2 * 4096];
    gemm128_body<2>(blockIdx.x, As, Bs, ab, WoT, meta, liveBt, grpSrc, grpOut,
                    (unsigned short*)0, (unsigned short*)0, (unsigned short*)0,
                    o_f);
}

// ---------------------------------------------------------------------------
// fused attention per live (bt,h) + zero-fill tail (blocks 1024..1151)
// ---------------------------------------------------------------------------
__global__ __launch_bounds__(256) void attn_kernel(
        const unsigned short* __restrict__ q,
        const unsigned short* __restrict__ kbuf,
        const unsigned short* __restrict__ vbuf,   // vT [bt][512][320]
        const int* __restrict__ meta,
        const int* __restrict__ liveBt,
        const int* __restrict__ maskN,
        unsigned short* __restrict__ ao,
        float* __restrict__ out_f) {
    int bid = blockIdx.x;
    if (bid >= 1024) {                             // zero-fill tail
        int bt = bid - 1024;
        if (maskN[bt]) return;
        float4* p = reinterpret_cast<float4*>(out_f + (size_t)bt * 65536);
        float4 z = make_float4(0.f, 0.f, 0.f, 0.f);
        #pragma unroll
        for (int k = 0; k < 64; k++) p[k * 256 + threadIdx.x] = z;
        return;
    }
    int L = meta[0] << 3;
    if (bid >= L) return;
    int wg = xcd_swz(bid, L);
    int i = wg >> 3, h = wg & 7;
    int bt = liveBt[i];
    int t = threadIdx.x, w = t >> 6, lane = t & 63;
    int lr = lane & 15, lg = lane >> 4;
    __shared__ __align__(16) unsigned short attn_s[4][16][328];

    const unsigned short* qrow = q + ((size_t)bt * 64 + w * 16 + lr) * 512 + h * 64;
    short8 qa0 = *reinterpret_cast<const short8*>(qrow + lg * 8);
    short8 qa1 = *reinterpret_cast<const short8*>(qrow + 32 + lg * 8);

    f32x4 acc[20];
    #pragma unroll
    for (int i2 = 0; i2 < 20; i2++) acc[i2] = (f32x4){0.f, 0.f, 0.f, 0.f};

    const unsigned short* kb = kbuf + (size_t)bt * NKEY_ * 512 + h * 64;
    #pragma unroll
    for (int nt2 = 0; nt2 < 20; nt2++) {
        const unsigned short* krow = kb + (size_t)(nt2 * 16 + lr) * 512;
        short8 b0 = *reinterpret_cast<const short8*>(krow + lg * 8);
        short8 b1 = *reinterpret_cast<const short8*>(krow + 32 + lg * 8);
        acc[nt2] = __builtin_amdgcn_mfma_f32_16x16x32_bf16(qa0, b0, acc[nt2], 0, 0, 0);
        acc[nt2] = __builtin_amdgcn_mfma_f32_16x16x32_bf16(qa1, b1, acc[nt2], 0, 0, 0);
    }

    float mx[4], sm[4];
    #pragma unroll
    for (int r = 0; r < 4; r++) mx[r] = -1e30f;
    #pragma unroll
    for (int nt2 = 0; nt2 < 20; nt2++)
        #pragma unroll
        for (int r = 0; r < 4; r++) mx[r] = fmaxf(mx[r], acc[nt2][r]);
    #pragma unroll
    for (int r = 0; r < 4; r++) {
        #pragma unroll
        for (int off = 1; off < 16; off <<= 1)
            mx[r] = fmaxf(mx[r], __shfl_xor(mx[r], off));
        sm[r] = 0.f;
    }
    #pragma unroll
    for (int nt2 = 0; nt2 < 20; nt2++)
        #pragma unroll
        for (int r = 0; r < 4; r++) {
            float p = __expf(acc[nt2][r] - mx[r]);
            acc[nt2][r] = p;
            sm[r] += p;
        }
    #pragma unroll
    for (int r = 0; r < 4; r++) {
        #pragma unroll
        for (int off = 1; off < 16; off <<= 1)
            sm[r] += __shfl_xor(sm[r], off);
        sm[r] = 1.0f / sm[r];
    }
    #pragma unroll
    for (int nt2 = 0; nt2 < 20; nt2++)
        #pragma unroll
        for (int r = 0; r < 4; r++)
            attn_s[w][lg * 4 + r][nt2 * 16 + lr] = f2bf(acc[nt2][r] * sm[r]);
    __syncthreads();

    f32x4 o[4];
    #pragma unroll
    for (int i2 = 0; i2 < 4; i2++) o[i2] = (f32x4){0.f, 0.f, 0.f, 0.f};
    const unsigned short* vb = vbuf + (size_t)bt * 512 * NKEY_ + (size_t)h * 64 * NKEY_;
    #pragma unroll
    for (int kc = 0; kc < 10; kc++) {
        short8 pa = *reinterpret_cast<const short8*>(&attn_s[w][lr][kc * 32 + lg * 8]);
        #pragma unroll
        for (int ni = 0; ni < 4; ni++) {
            short8 vf = *reinterpret_cast<const short8*>(
                vb + (size_t)(ni * 16 + lr) * NKEY_ + kc * 32 + lg * 8);
            o[ni] = __builtin_amdgcn_mfma_f32_16x16x32_bf16(pa, vf, o[ni], 0, 0, 0);
        }
    }
    #pragma unroll
    for (int ni = 0; ni < 4; ni++)
        #pragma unroll
        for (int r = 0; r < 4; r++)
            ao[((size_t)bt * 64 + w * 16 + lg * 4 + r) * 512 + h * 64 + ni * 16 + lr] =
                f2bf(o[ni][r]);
}

// ---------------------------------------------------------------------------
extern "C" void kernel_launch(void* const* d_in, const int* in_sizes, int n_in,
                              void* d_out, int out_size, void* d_ws, size_t ws_size,
                              hipStream_t stream) {
    const float* x            = (const float*)d_in[0];
    const float* lat          = (const float*)d_in[1];
    const unsigned char* mraw = (const unsigned char*)d_in[2];
    const float* gm           = (const float*)d_in[3];
    const float* bm           = (const float*)d_in[4];
    const float* gl           = (const float*)d_in[5];
    const float* bl           = (const float*)d_in[6];
    const float* Wq           = (const float*)d_in[7];
    const float* Wkv          = (const float*)d_in[8];
    const float* Wo           = (const float*)d_in[9];
    float* out = (float*)d_out;

    char* ws = (char*)d_ws;
    int* maskN  = (int*)(ws + 0);          // 512 B
    int* meta   = (int*)(ws + 512);        // 64 B
    int* liveBt = (int*)(ws + 1024);       // 640 B
    int* grpSrc = (int*)(ws + 2048);       // ~2.6 KB
    int* grpOut = (int*)(ws + 5120);       // ~2.6 KB
    size_t off = 8192;
    unsigned short* WqT  = (unsigned short*)(ws + off); off += 1048576;   // 512*1024*2
    unsigned short* WkvT = (unsigned short*)(ws + off); off += 2097152;   // 1024*1024*2
    unsigned short* WoT  = (unsigned short*)(ws + off); off += 1048576;   // 1024*512*2
    unsigned short* kvin = (unsigned short*)(ws + off); off += 83886080;  // 128*320*1024*2
    unsigned short* qb   = (unsigned short*)(ws + off); off += 8388608;   // 128*64*512*2
    unsigned short* kb   = (unsigned short*)(ws + off); off += 41943040;  // 128*320*512*2
    unsigned short* vb   = (unsigned short*)(ws + off); off += 41943040;  // 128*512*320*2
    unsigned short* ab   = (unsigned short*)(ws + off); off += 8388608;   // 128*64*512*2

    hipLaunchKernelGGL(prep_ln_kernel, dim3(49153), dim3(256), 0, stream,
                       Wq, Wkv, Wo, mraw, x, lat, gm, bm, gl, bl,
                       WqT, WkvT, WoT, kvin, maskN, meta, liveBt, grpSrc, grpOut);
    hipLaunchKernelGGL(gemm_kvq_kernel, dim3(2816), dim3(256), 0, stream,
                       kvin, WkvT, WqT, meta, liveBt, grpSrc, grpOut,
                       qb, kb, vb);
    hipLaunchKernelGGL(attn_kernel,     dim3(1152), dim3(256), 0, stream,
                       qb, kb, vb, meta, liveBt, maskN, ab, out);
    hipLaunchKernelGGL(gemm_out_kernel, dim3(512),  dim3(256), 0, stream,
                       ab, WoT, meta, liveBt, grpSrc, grpOut, out);
}